// Round 2
// baseline (533.963 us; speedup 1.0000x reference)
//
#include <hip/hip_runtime.h>
#include <hip/hip_bf16.h>
#include <math.h>

#define B_ 2
#define S_ 2048
#define D_ 1024
#define H_ 16
#define DH_ 64
#define DFF_ 4096
#define M_ (B_*S_)

typedef __bf16 bf16;
typedef __bf16 bf16x8 __attribute__((ext_vector_type(8)));
typedef __bf16 bf16x4 __attribute__((ext_vector_type(4)));
typedef float f32x4 __attribute__((ext_vector_type(4)));

__device__ __forceinline__ void gll16(const void* g, void* l) {
  __builtin_amdgcn_global_load_lds(
      (const __attribute__((address_space(1))) void*)g,
      (__attribute__((address_space(3))) void*)l, 16, 0, 0);
}

// ---------------- RMSNorm: fp32 [rows, D] -> bf16 ----------------
__global__ __launch_bounds__(256) void rmsnorm_kernel(const float* __restrict__ x,
    const float* __restrict__ scale, bf16* __restrict__ out) {
  __shared__ float red[4];
  int row = blockIdx.x, t = threadIdx.x;
  const float4* xr = (const float4*)(x + (size_t)row * D_);
  float4 v = xr[t];
  float ss = v.x*v.x + v.y*v.y + v.z*v.z + v.w*v.w;
  #pragma unroll
  for (int off = 32; off > 0; off >>= 1) ss += __shfl_down(ss, off, 64);
  if ((t & 63) == 0) red[t >> 6] = ss;
  __syncthreads();
  float tot = red[0] + red[1] + red[2] + red[3];
  float r = rsqrtf(tot * (1.0f / D_) + 1e-8f);
  float4 sc = ((const float4*)scale)[t];
  bf16x4 o;
  o[0] = (bf16)(v.x * sc.x * r);
  o[1] = (bf16)(v.y * sc.y * r);
  o[2] = (bf16)(v.z * sc.z * r);
  o[3] = (bf16)(v.w * sc.w * r);
  *(bf16x4*)(out + (size_t)row * D_ + t * 4) = o;
}

// ---------------- Weight transpose: fp32 [K,N] -> bf16 [N,K] ----------------
__global__ __launch_bounds__(256) void wtrans_kernel(const float* __restrict__ W,
    bf16* __restrict__ Wt, int K, int N) {
  __shared__ float tile[32][33];
  int n0 = blockIdx.x * 32, k0 = blockIdx.y * 32;
  int tx = threadIdx.x & 31, ty = threadIdx.x >> 5;
  #pragma unroll
  for (int i = 0; i < 4; i++)
    tile[ty + i*8][tx] = W[(size_t)(k0 + ty + i*8) * N + n0 + tx];
  __syncthreads();
  #pragma unroll
  for (int i = 0; i < 4; i++)
    Wt[(size_t)(n0 + ty + i*8) * K + k0 + tx] = (bf16)tile[tx][ty + i*8];
}

// ---------------- V transpose: bf16 [B*H][S,DH] -> [B*H][DH,S] ----------------
__global__ __launch_bounds__(256) void vtrans_kernel(const bf16* __restrict__ Vin,
    bf16* __restrict__ Vt) {
  __shared__ bf16 tile[32][34];
  size_t base = (size_t)blockIdx.z * (S_ * DH_);
  int s0 = blockIdx.x * 32, d0 = blockIdx.y * 32;
  int tx = threadIdx.x & 31, ty = threadIdx.x >> 5;
  #pragma unroll
  for (int i = 0; i < 4; i++)
    tile[ty + i*8][tx] = Vin[base + (size_t)(s0 + ty + i*8) * DH_ + d0 + tx];
  __syncthreads();
  #pragma unroll
  for (int i = 0; i < 4; i++)
    Vt[base + (size_t)(d0 + ty + i*8) * S_ + s0 + tx] = tile[tx][ty + i*8];
}

__device__ __forceinline__ float gelu_exact(float v) {
  return 0.5f * v * (1.0f + erff(v * 0.70710678118654752f));
}

// ---------------- GEMM: C[M,N] = A[M,K](bf16) @ Bt[N,K]^T + bias, epilogue ----------------
// MODE 0: qkv scatter to [3][B,H,S,DH] bf16
// MODE 1: fp32 out = acc + bias + res   (out-proj + residual)
// MODE 2: bf16 out = gelu(acc + bias)   (ffn1)
// MODE 3: fp32 out = acc + bias + res   (ffn2 + residual -> d_out)
template<int MODE>
__global__ __launch_bounds__(256) void gemm_kernel(
    const bf16* __restrict__ A, const bf16* __restrict__ Bt,
    const float* __restrict__ bias, const float* __restrict__ res,
    void* __restrict__ outp, int M, int N, int K) {
  __shared__ __align__(16) bf16 As[128 * 32];
  __shared__ __align__(16) bf16 Bs[128 * 32];
  int t = threadIdx.x;
  int wave = t >> 6, lane = t & 63;
  int lm = lane & 15, lg = lane >> 4;
  int m0 = blockIdx.y * 128, n0 = blockIdx.x * 128;
  int wm = (wave >> 1) * 64, wn = (wave & 1) * 64;
  f32x4 acc[4][4] = {};

  const bf16* Ag = A + (size_t)(m0 + (t >> 2)) * K + (t & 3) * 8;
  const bf16* Bg = Bt + (size_t)(n0 + (t >> 2)) * K + (t & 3) * 8;

  for (int k0 = 0; k0 < K; k0 += 32) {
    __syncthreads();   // prior iteration's readers done
    gll16(Ag + k0, As + t * 8);
    gll16(Ag + k0 + (size_t)64 * K, As + 2048 + t * 8);
    gll16(Bg + k0, Bs + t * 8);
    gll16(Bg + k0 + (size_t)64 * K, Bs + 2048 + t * 8);
    __syncthreads();   // drains vmcnt before barrier release
    bf16x8 af[4], bfr[4];
    #pragma unroll
    for (int i = 0; i < 4; i++)
      af[i] = *(const bf16x8*)(As + (wm + i * 16 + lm) * 32 + lg * 8);
    #pragma unroll
    for (int j = 0; j < 4; j++)
      bfr[j] = *(const bf16x8*)(Bs + (wn + j * 16 + lm) * 32 + lg * 8);
    #pragma unroll
    for (int i = 0; i < 4; i++)
      #pragma unroll
      for (int j = 0; j < 4; j++)
        acc[i][j] = __builtin_amdgcn_mfma_f32_16x16x32_bf16(af[i], bfr[j], acc[i][j], 0, 0, 0);
  }

  #pragma unroll
  for (int i = 0; i < 4; i++) {
    int row = m0 + wm + i * 16 + lg * 4;
    #pragma unroll
    for (int j = 0; j < 4; j++) {
      int col = n0 + wn + j * 16 + lm;
      float bcol = bias[col];
      #pragma unroll
      for (int r = 0; r < 4; r++) {
        float v = acc[i][j][r] + bcol;
        int rr = row + r;
        if (MODE == 0) {
          int which = col >> 10, d = col & 1023;
          int hh = d >> 6, dh = d & 63;
          int bb = rr >> 11, s = rr & 2047;
          ((bf16*)outp)[(size_t)which * ((size_t)B_*H_*S_*DH_) +
              ((size_t)(bb * H_ + hh) * S_ + s) * DH_ + dh] = (bf16)v;
        } else if (MODE == 1) {
          ((float*)outp)[(size_t)rr * N + col] = v + res[(size_t)rr * N + col];
        } else if (MODE == 2) {
          ((bf16*)outp)[(size_t)rr * N + col] = (bf16)gelu_exact(v);
        } else {
          ((float*)outp)[(size_t)rr * N + col] = v + res[(size_t)rr * N + col];
        }
      }
    }
  }
}

// ---------------- Flash attention v2 ----------------
// Q-tile 128/block (32 q-rows per wave as 2 m-frags), KV-tile 64,
// register prefetch of next K/V tile overlaps global latency with compute.
// q,k [B,H,S,DH], vT [B,H,DH,S] -> ao [B,S,D] bf16
#define PSTR 68   // P row stride: 2s mod 32 == 8 -> conflict-free scalar writes
__global__ __launch_bounds__(256, 3) void attn_kernel(
    const bf16* __restrict__ q, const bf16* __restrict__ k,
    const bf16* __restrict__ vT, bf16* __restrict__ ao) {
  __shared__ __align__(16) bf16 Ks[64 * 72];
  __shared__ __align__(16) bf16 Vs[64 * 72];           // [dh][kv]
  __shared__ __align__(16) bf16 Ps[4 * 32 * PSTR];     // per-wave 32 q-rows
  int t = threadIdx.x, wave = t >> 6, lane = t & 63;
  int lm = lane & 15, lg = lane >> 4;
  int q0 = blockIdx.x * 128;
  int h = blockIdx.y, b = blockIdx.z;
  size_t base = (size_t)(b * H_ + h) * ((size_t)S_ * DH_);
  const bf16* Q = q + base;
  const bf16* K = k + base;
  const bf16* V = vT + base;   // [DH][S]
  const float LOG2E = 1.4426950408889634f;
  float slope = exp2f(-0.5f * (float)(h + 1)) * LOG2E;
  const float qscale = 0.125f * LOG2E;

  // Q fragments in registers, pre-scaled (folds 1/sqrt(dh) and log2e)
  bf16x8 qf[2][2];
  #pragma unroll
  for (int i = 0; i < 2; i++)
    #pragma unroll
    for (int h2 = 0; h2 < 2; h2++) {
      bf16x8 v = *(const bf16x8*)(Q + (size_t)(q0 + wave * 32 + i * 16 + lm) * DH_ + h2 * 32 + lg * 8);
      #pragma unroll
      for (int e = 0; e < 8; e++) v[e] = (bf16)((float)v[e] * qscale);
      qf[i][h2] = v;
    }

  int sr = t >> 3, scol = (t & 7) * 8;   // staging row/col (row += 32 for it=1)
  uint4 kr[2], vr[2];
  #pragma unroll
  for (int it = 0; it < 2; it++) {
    kr[it] = *(const uint4*)(K + (size_t)(sr + it * 32) * DH_ + scol);
    vr[it] = *(const uint4*)(V + (size_t)(sr + it * 32) * S_ + scol);
  }

  f32x4 oacc[2][4] = {};
  float mrun[2][4], lrun[2][4];
  #pragma unroll
  for (int i = 0; i < 2; i++)
    #pragma unroll
    for (int r = 0; r < 4; r++) { mrun[i][r] = -INFINITY; lrun[i][r] = 0.f; }

  for (int j0 = 0; j0 < S_; j0 += 64) {
    __syncthreads();   // prior iteration's LDS readers done
    #pragma unroll
    for (int it = 0; it < 2; it++) {
      *(uint4*)(Ks + (sr + it * 32) * 72 + scol) = kr[it];
      *(uint4*)(Vs + (sr + it * 32) * 72 + scol) = vr[it];
    }
    __syncthreads();
    if (j0 + 64 < S_) {
      #pragma unroll
      for (int it = 0; it < 2; it++) {
        kr[it] = *(const uint4*)(K + (size_t)(j0 + 64 + sr + it * 32) * DH_ + scol);
        vr[it] = *(const uint4*)(V + (size_t)(sr + it * 32) * S_ + j0 + 64 + scol);
      }
    }

    #pragma unroll
    for (int i = 0; i < 2; i++) {
      f32x4 sc[4];
      #pragma unroll
      for (int tt = 0; tt < 4; tt++) {
        f32x4 a = {};
        bf16x8 kb0 = *(const bf16x8*)(Ks + (tt * 16 + lm) * 72 + lg * 8);
        bf16x8 kb1 = *(const bf16x8*)(Ks + (tt * 16 + lm) * 72 + 32 + lg * 8);
        a = __builtin_amdgcn_mfma_f32_16x16x32_bf16(qf[i][0], kb0, a, 0, 0, 0);
        a = __builtin_amdgcn_mfma_f32_16x16x32_bf16(qf[i][1], kb1, a, 0, 0, 0);
        sc[tt] = a;
      }
      float mx[4] = {-INFINITY, -INFINITY, -INFINITY, -INFINITY};
      int qrow = q0 + wave * 32 + i * 16 + lg * 4;
      #pragma unroll
      for (int tt = 0; tt < 4; tt++) {
        int kcol = j0 + tt * 16 + lm;
        #pragma unroll
        for (int r = 0; r < 4; r++) {
          float s = sc[tt][r] - slope * fabsf((float)(qrow + r - kcol));
          sc[tt][r] = s;
          mx[r] = fmaxf(mx[r], s);
        }
      }
      #pragma unroll
      for (int r = 0; r < 4; r++) {
        #pragma unroll
        for (int off = 1; off < 16; off <<= 1)
          mx[r] = fmaxf(mx[r], __shfl_xor(mx[r], off, 16));
      }
      float al[4], rs[4] = {0.f, 0.f, 0.f, 0.f};
      #pragma unroll
      for (int r = 0; r < 4; r++) {
        float mn = fmaxf(mrun[i][r], mx[r]);
        al[r] = __builtin_amdgcn_exp2f(mrun[i][r] - mn);
        mrun[i][r] = mn;
      }
      bf16* Pw = Ps + wave * (32 * PSTR) + i * (16 * PSTR);
      #pragma unroll
      for (int tt = 0; tt < 4; tt++)
        #pragma unroll
        for (int r = 0; r < 4; r++) {
          float p = __builtin_amdgcn_exp2f(sc[tt][r] - mrun[i][r]);
          rs[r] += p;
          Pw[(lg * 4 + r) * PSTR + tt * 16 + lm] = (bf16)p;
        }
      #pragma unroll
      for (int r = 0; r < 4; r++) {
        #pragma unroll
        for (int off = 1; off < 16; off <<= 1)
          rs[r] += __shfl_xor(rs[r], off, 16);
        lrun[i][r] = lrun[i][r] * al[r] + rs[r];
      }
      #pragma unroll
      for (int tt = 0; tt < 4; tt++)
        #pragma unroll
        for (int r = 0; r < 4; r++)
          oacc[i][tt][r] *= al[r];

      bf16x8 ap0 = *(const bf16x8*)(Pw + lm * PSTR + lg * 8);
      bf16x8 ap1 = *(const bf16x8*)(Pw + lm * PSTR + 32 + lg * 8);
      #pragma unroll
      for (int tt = 0; tt < 4; tt++) {
        bf16x8 vb0 = *(const bf16x8*)(Vs + (tt * 16 + lm) * 72 + lg * 8);
        bf16x8 vb1 = *(const bf16x8*)(Vs + (tt * 16 + lm) * 72 + 32 + lg * 8);
        oacc[i][tt] = __builtin_amdgcn_mfma_f32_16x16x32_bf16(ap0, vb0, oacc[i][tt], 0, 0, 0);
        oacc[i][tt] = __builtin_amdgcn_mfma_f32_16x16x32_bf16(ap1, vb1, oacc[i][tt], 0, 0, 0);
      }
    }
  }

  #pragma unroll
  for (int i = 0; i < 2; i++)
    #pragma unroll
    for (int r = 0; r < 4; r++) {
      float inv = 1.0f / lrun[i][r];
      int row = q0 + wave * 32 + i * 16 + lg * 4 + r;
      #pragma unroll
      for (int tt = 0; tt < 4; tt++) {
        int col = h * 64 + tt * 16 + lm;
        ao[((size_t)(b * S_) + row) * D_ + col] = (bf16)(oacc[i][tt][r] * inv);
      }
    }
}

extern "C" void kernel_launch(void* const* d_in, const int* in_sizes, int n_in,
                              void* d_out, int out_size, void* d_ws, size_t ws_size,
                              hipStream_t stream) {
  const float* x      = (const float*)d_in[0];
  const float* scale1 = (const float*)d_in[1];
  const float* scale2 = (const float*)d_in[2];
  const float* w_qkv  = (const float*)d_in[3];
  const float* b_qkv  = (const float*)d_in[4];
  const float* w_out  = (const float*)d_in[5];
  const float* b_out  = (const float*)d_in[6];
  const float* w1     = (const float*)d_in[7];
  const float* b1     = (const float*)d_in[8];
  const float* w2     = (const float*)d_in[9];
  const float* b2     = (const float*)d_in[10];

  char* ws = (char*)d_ws;
  const size_t MB = 1024 * 1024;
  bf16* xn    = (bf16*)(ws + 0);        // 8MB [M,D]; reused as ao after qkv gemm
  bf16* qb    = (bf16*)(ws + 8*MB);     // 8MB q [B,H,S,DH]; reused as xn2 after attn
  bf16* kb    = (bf16*)(ws + 16*MB);    // 8MB k
  bf16* vb    = (bf16*)(ws + 24*MB);    // 8MB v
  bf16* vT    = (bf16*)(ws + 32*MB);    // 8MB v transposed [B,H,DH,S]
  bf16* wqkvT = (bf16*)(ws + 40*MB);    // 6MB
  bf16* woutT = (bf16*)(ws + 46*MB);    // 2MB
  bf16* w1T   = (bf16*)(ws + 48*MB);    // 8MB
  bf16* w2T   = (bf16*)(ws + 56*MB);    // 8MB
  float* x2   = (float*)(ws + 64*MB);   // 16MB fp32 [M,D]
  bf16* xn2   = qb;                     // reuse (q dead after attention)
  bf16* hbuf  = (bf16*)(ws + 16*MB);    // 32MB [M,DFF]; reuses k,v,vT,wqkvT,woutT
  bf16* ao    = xn;

  dim3 blk(256);
  wtrans_kernel<<<dim3(3072/32, 1024/32), blk, 0, stream>>>(w_qkv, wqkvT, 1024, 3072);
  wtrans_kernel<<<dim3(1024/32, 1024/32), blk, 0, stream>>>(w_out, woutT, 1024, 1024);
  wtrans_kernel<<<dim3(4096/32, 1024/32), blk, 0, stream>>>(w1, w1T, 1024, 4096);
  wtrans_kernel<<<dim3(1024/32, 4096/32), blk, 0, stream>>>(w2, w2T, 4096, 1024);

  rmsnorm_kernel<<<dim3(M_), blk, 0, stream>>>(x, scale1, xn);

  gemm_kernel<0><<<dim3(3072/128, M_/128), blk, 0, stream>>>(
      xn, wqkvT, b_qkv, nullptr, qb, M_, 3072, 1024);

  vtrans_kernel<<<dim3(S_/32, DH_/32, B_*H_), blk, 0, stream>>>(vb, vT);

  attn_kernel<<<dim3(S_/128, H_, B_), blk, 0, stream>>>(qb, kb, vT, ao);

  gemm_kernel<1><<<dim3(1024/128, M_/128), blk, 0, stream>>>(
      ao, woutT, b_out, x, x2, M_, 1024, 1024);

  rmsnorm_kernel<<<dim3(M_), blk, 0, stream>>>(x2, scale2, xn2);

  gemm_kernel<2><<<dim3(4096/128, M_/128), blk, 0, stream>>>(
      xn2, w1T, b1, nullptr, hbuf, M_, 4096, 1024);

  gemm_kernel<3><<<dim3(1024/128, M_/128), blk, 0, stream>>>(
      hbuf, w2T, b2, x2, d_out, M_, 1024, 4096);
}

// Round 3
// 484.400 us; speedup vs baseline: 1.1023x; 1.1023x over previous
//
#include <hip/hip_runtime.h>
#include <hip/hip_bf16.h>
#include <math.h>

#define B_ 2
#define S_ 2048
#define D_ 1024
#define H_ 16
#define DH_ 64
#define DFF_ 4096
#define M_ (B_*S_)

typedef __bf16 bf16;
typedef __bf16 bf16x8 __attribute__((ext_vector_type(8)));
typedef __bf16 bf16x4 __attribute__((ext_vector_type(4)));
typedef float f32x4 __attribute__((ext_vector_type(4)));

__device__ __forceinline__ void gll16(const void* g, void* l) {
  __builtin_amdgcn_global_load_lds(
      (const __attribute__((address_space(1))) void*)g,
      (__attribute__((address_space(3))) void*)l, 16, 0, 0);
}

// ---------------- RMSNorm: fp32 [rows, D] -> bf16 ----------------
__global__ __launch_bounds__(256) void rmsnorm_kernel(const float* __restrict__ x,
    const float* __restrict__ scale, bf16* __restrict__ out) {
  __shared__ float red[4];
  int row = blockIdx.x, t = threadIdx.x;
  const float4* xr = (const float4*)(x + (size_t)row * D_);
  float4 v = xr[t];
  float ss = v.x*v.x + v.y*v.y + v.z*v.z + v.w*v.w;
  #pragma unroll
  for (int off = 32; off > 0; off >>= 1) ss += __shfl_down(ss, off, 64);
  if ((t & 63) == 0) red[t >> 6] = ss;
  __syncthreads();
  float tot = red[0] + red[1] + red[2] + red[3];
  float r = rsqrtf(tot * (1.0f / D_) + 1e-8f);
  float4 sc = ((const float4*)scale)[t];
  bf16x4 o;
  o[0] = (bf16)(v.x * sc.x * r);
  o[1] = (bf16)(v.y * sc.y * r);
  o[2] = (bf16)(v.z * sc.z * r);
  o[3] = (bf16)(v.w * sc.w * r);
  *(bf16x4*)(out + (size_t)row * D_ + t * 4) = o;
}

// ---------------- add bias + residual init: dst = src + bias (rows x 1024) ----------------
__global__ __launch_bounds__(256) void addbias_kernel(const float* __restrict__ src,
    const float* __restrict__ bias, float* __restrict__ dst) {
  int row = blockIdx.x, t = threadIdx.x;
  float4 s = ((const float4*)(src + (size_t)row * D_))[t];
  float4 bv = ((const float4*)bias)[t];
  float4 o; o.x = s.x + bv.x; o.y = s.y + bv.y; o.z = s.z + bv.z; o.w = s.w + bv.w;
  ((float4*)(dst + (size_t)row * D_))[t] = o;
}

// ---------------- Weight transpose: fp32 [K,N] -> bf16 [N,K] ----------------
__global__ __launch_bounds__(256) void wtrans_kernel(const float* __restrict__ W,
    bf16* __restrict__ Wt, int K, int N) {
  __shared__ float tile[32][33];
  int n0 = blockIdx.x * 32, k0 = blockIdx.y * 32;
  int tx = threadIdx.x & 31, ty = threadIdx.x >> 5;
  #pragma unroll
  for (int i = 0; i < 4; i++)
    tile[ty + i*8][tx] = W[(size_t)(k0 + ty + i*8) * N + n0 + tx];
  __syncthreads();
  #pragma unroll
  for (int i = 0; i < 4; i++)
    Wt[(size_t)(n0 + ty + i*8) * K + k0 + tx] = (bf16)tile[tx][ty + i*8];
}

// ---------------- V transpose: bf16 [B*H][S,DH] -> [B*H][DH,S] ----------------
__global__ __launch_bounds__(256) void vtrans_kernel(const bf16* __restrict__ Vin,
    bf16* __restrict__ Vt) {
  __shared__ bf16 tile[32][34];
  size_t base = (size_t)blockIdx.z * (S_ * DH_);
  int s0 = blockIdx.x * 32, d0 = blockIdx.y * 32;
  int tx = threadIdx.x & 31, ty = threadIdx.x >> 5;
  #pragma unroll
  for (int i = 0; i < 4; i++)
    tile[ty + i*8][tx] = Vin[base + (size_t)(s0 + ty + i*8) * DH_ + d0 + tx];
  __syncthreads();
  #pragma unroll
  for (int i = 0; i < 4; i++)
    Vt[base + (size_t)(d0 + ty + i*8) * S_ + s0 + tx] = tile[tx][ty + i*8];
}

__device__ __forceinline__ float gelu_exact(float v) {
  return 0.5f * v * (1.0f + erff(v * 0.70710678118654752f));
}

// ---------------- GEMM: C[M,N] = A[M,Ktot] @ Bt[N,Ktot]^T over k-slice ----------------
// MODE 0: qkv scatter to [3][B,H,S,DH] bf16 (+bias)
// MODE 2: bf16 out = gelu(acc + bias)   (ffn1)
// MODE 4: fp32 unsafeAtomicAdd into outp (split-K; bias pre-applied by addbias)
template<int MODE>
__global__ __launch_bounds__(256) void gemm_kernel(
    const bf16* __restrict__ A, const bf16* __restrict__ Bt,
    const float* __restrict__ bias, void* __restrict__ outp,
    int M, int N, int K, int lda) {
  __shared__ __align__(16) bf16 As[128 * 32];
  __shared__ __align__(16) bf16 Bs[128 * 32];
  int t = threadIdx.x;
  int wave = t >> 6, lane = t & 63;
  int lm = lane & 15, lg = lane >> 4;
  int m0 = blockIdx.y * 128, n0 = blockIdx.x * 128;
  size_t koff = (size_t)blockIdx.z * K;
  int wm = (wave >> 1) * 64, wn = (wave & 1) * 64;
  f32x4 acc[4][4] = {};

  const bf16* Ag = A + (size_t)(m0 + (t >> 2)) * lda + koff + (t & 3) * 8;
  const bf16* Bg = Bt + (size_t)(n0 + (t >> 2)) * lda + koff + (t & 3) * 8;

  for (int k0 = 0; k0 < K; k0 += 32) {
    __syncthreads();
    gll16(Ag + k0, As + t * 8);
    gll16(Ag + k0 + (size_t)64 * lda, As + 2048 + t * 8);
    gll16(Bg + k0, Bs + t * 8);
    gll16(Bg + k0 + (size_t)64 * lda, Bs + 2048 + t * 8);
    __syncthreads();
    bf16x8 af[4], bfr[4];
    #pragma unroll
    for (int i = 0; i < 4; i++)
      af[i] = *(const bf16x8*)(As + (wm + i * 16 + lm) * 32 + lg * 8);
    #pragma unroll
    for (int j = 0; j < 4; j++)
      bfr[j] = *(const bf16x8*)(Bs + (wn + j * 16 + lm) * 32 + lg * 8);
    #pragma unroll
    for (int i = 0; i < 4; i++)
      #pragma unroll
      for (int j = 0; j < 4; j++)
        acc[i][j] = __builtin_amdgcn_mfma_f32_16x16x32_bf16(af[i], bfr[j], acc[i][j], 0, 0, 0);
  }

  #pragma unroll
  for (int i = 0; i < 4; i++) {
    int row = m0 + wm + i * 16 + lg * 4;
    #pragma unroll
    for (int j = 0; j < 4; j++) {
      int col = n0 + wn + j * 16 + lm;
      float bcol = (MODE == 4) ? 0.f : bias[col];
      #pragma unroll
      for (int r = 0; r < 4; r++) {
        float v = acc[i][j][r] + bcol;
        int rr = row + r;
        if (MODE == 0) {
          int which = col >> 10, d = col & 1023;
          int hh = d >> 6, dh = d & 63;
          int bb = rr >> 11, s = rr & 2047;
          ((bf16*)outp)[(size_t)which * ((size_t)B_*H_*S_*DH_) +
              ((size_t)(bb * H_ + hh) * S_ + s) * DH_ + dh] = (bf16)v;
        } else if (MODE == 2) {
          ((bf16*)outp)[(size_t)rr * N + col] = (bf16)gelu_exact(v);
        } else {
          unsafeAtomicAdd(&((float*)outp)[(size_t)rr * N + col], v);
        }
      }
    }
  }
}

// ---------------- Flash attention v3 ----------------
// 64 q-rows/block (16 per wave), KV tile 64, fixed-max softmax (no online max),
// gll16 staging with XOR-granule swizzle (swizzle applied on global source side).
// q,k [B,H,S,DH], vT [B,H,DH,S] -> ao [B,S,D] bf16
#define PSTR 68
__global__ __launch_bounds__(256, 4) void attn_kernel(
    const bf16* __restrict__ q, const bf16* __restrict__ k,
    const bf16* __restrict__ vT, bf16* __restrict__ ao) {
  __shared__ __align__(16) bf16 Ks[64 * 64];          // granule-swizzled
  __shared__ __align__(16) bf16 Vs[64 * 64];          // granule-swizzled [dh][kv]
  __shared__ __align__(16) bf16 Ps[4 * 16 * PSTR];
  int t = threadIdx.x, wave = t >> 6, lane = t & 63;
  int lm = lane & 15, lg = lane >> 4;
  int q0 = blockIdx.x * 64;
  int h = blockIdx.y, b = blockIdx.z;
  size_t base = (size_t)(b * H_ + h) * ((size_t)S_ * DH_);
  const bf16* Q = q + base;
  const bf16* K = k + base;
  const bf16* V = vT + base;   // [DH][S]
  const float LOG2E = 1.4426950408889634f;
  float nslope = -exp2f(-0.5f * (float)(h + 1)) * LOG2E;
  const float qscale = 0.125f * LOG2E;
  const float FMAX = 8.0f;     // fixed softmax max (log2 domain)

  // Q fragments, pre-scaled
  bf16x8 qf[2];
  #pragma unroll
  for (int h2 = 0; h2 < 2; h2++) {
    bf16x8 v = *(const bf16x8*)(Q + (size_t)(q0 + wave * 16 + lm) * DH_ + h2 * 32 + lg * 8);
    #pragma unroll
    for (int e = 0; e < 8; e++) v[e] = (bf16)((float)v[e] * qscale);
    qf[h2] = v;
  }

  // staging: granule gi = it*256 + t maps to (row = gi>>3, slot = gi&7);
  // LDS slot (row, j) holds global granule (row, j ^ (row&7)).
  int row0 = t >> 3, jslot = t & 7;
  int gsw = (jslot ^ (row0 & 7)) << 3;
  const bf16* Ksrc0 = K + (size_t)row0 * DH_ + gsw;
  const bf16* Vsrc0 = V + (size_t)row0 * S_ + gsw;

  f32x4 oacc[4] = {};
  float rs[4] = {0.f, 0.f, 0.f, 0.f};
  int psw = lm & 7;

  for (int jt = 0; jt < S_; jt += 64) {
    __syncthreads();   // prior tile's readers done
    gll16(Ksrc0 + (size_t)jt * DH_, Ks + (size_t)t * 8);
    gll16(Ksrc0 + (size_t)(jt + 32) * DH_, Ks + (size_t)(t + 256) * 8);
    gll16(Vsrc0 + jt, Vs + (size_t)t * 8);
    gll16(Vsrc0 + (size_t)32 * S_ + jt, Vs + (size_t)(t + 256) * 8);
    __syncthreads();   // drains vmcnt

    // QK^T (C initialized to -FMAX to fold the fixed max)
    f32x4 sc[4];
    #pragma unroll
    for (int tt = 0; tt < 4; tt++) {
      f32x4 a = {-FMAX, -FMAX, -FMAX, -FMAX};
      int krow = tt * 16 + lm;
      bf16x8 kb0 = *(const bf16x8*)(Ks + (size_t)(krow * 8 + (lg ^ psw)) * 8);
      bf16x8 kb1 = *(const bf16x8*)(Ks + (size_t)(krow * 8 + ((lg + 4) ^ psw)) * 8);
      a = __builtin_amdgcn_mfma_f32_16x16x32_bf16(qf[0], kb0, a, 0, 0, 0);
      a = __builtin_amdgcn_mfma_f32_16x16x32_bf16(qf[1], kb1, a, 0, 0, 0);
      sc[tt] = a;
    }

    // fixed-max softmax: p = exp2(s + alibi - FMAX); plain accumulation
    bf16* Pw = Ps + wave * (16 * PSTR);
    int i0 = q0 + wave * 16 + lg * 4;
    #pragma unroll
    for (int tt = 0; tt < 4; tt++) {
      float f0 = (float)(i0 - jt - tt * 16 - lm);
      #pragma unroll
      for (int r = 0; r < 4; r++) {
        float s2 = fmaf(nslope, fabsf(f0 + (float)r), sc[tt][r]);
        float p = __builtin_amdgcn_exp2f(s2);
        rs[r] += p;
        Pw[(lg * 4 + r) * PSTR + tt * 16 + lm] = (bf16)p;
      }
    }

    // PV
    bf16x8 ap0 = *(const bf16x8*)(Pw + lm * PSTR + lg * 8);
    bf16x8 ap1 = *(const bf16x8*)(Pw + lm * PSTR + 32 + lg * 8);
    #pragma unroll
    for (int tt = 0; tt < 4; tt++) {
      int vrow = tt * 16 + lm;
      bf16x8 vb0 = *(const bf16x8*)(Vs + (size_t)(vrow * 8 + (lg ^ psw)) * 8);
      bf16x8 vb1 = *(const bf16x8*)(Vs + (size_t)(vrow * 8 + ((lg + 4) ^ psw)) * 8);
      oacc[tt] = __builtin_amdgcn_mfma_f32_16x16x32_bf16(ap0, vb0, oacc[tt], 0, 0, 0);
      oacc[tt] = __builtin_amdgcn_mfma_f32_16x16x32_bf16(ap1, vb1, oacc[tt], 0, 0, 0);
    }
  }

  // one final l-reduction across the 16 lm lanes
  #pragma unroll
  for (int r = 0; r < 4; r++) {
    #pragma unroll
    for (int off = 1; off < 16; off <<= 1)
      rs[r] += __shfl_xor(rs[r], off, 16);
  }

  #pragma unroll
  for (int r = 0; r < 4; r++) {
    float inv = 1.0f / rs[r];
    int row = q0 + wave * 16 + lg * 4 + r;
    #pragma unroll
    for (int tt = 0; tt < 4; tt++) {
      int col = h * 64 + tt * 16 + lm;
      ao[((size_t)(b * S_) + row) * D_ + col] = (bf16)(oacc[tt][r] * inv);
    }
  }
}

extern "C" void kernel_launch(void* const* d_in, const int* in_sizes, int n_in,
                              void* d_out, int out_size, void* d_ws, size_t ws_size,
                              hipStream_t stream) {
  const float* x      = (const float*)d_in[0];
  const float* scale1 = (const float*)d_in[1];
  const float* scale2 = (const float*)d_in[2];
  const float* w_qkv  = (const float*)d_in[3];
  const float* b_qkv  = (const float*)d_in[4];
  const float* w_out  = (const float*)d_in[5];
  const float* b_out  = (const float*)d_in[6];
  const float* w1     = (const float*)d_in[7];
  const float* b1     = (const float*)d_in[8];
  const float* w2     = (const float*)d_in[9];
  const float* b2     = (const float*)d_in[10];

  char* ws = (char*)d_ws;
  const size_t MB = 1024 * 1024;
  bf16* xn    = (bf16*)(ws + 0);        // 8MB [M,D]; reused as ao after qkv gemm
  bf16* qb    = (bf16*)(ws + 8*MB);     // 8MB q [B,H,S,DH]; reused as xn2 after attn
  bf16* kb    = (bf16*)(ws + 16*MB);    // 8MB k
  bf16* vb    = (bf16*)(ws + 24*MB);    // 8MB v
  bf16* vT    = (bf16*)(ws + 32*MB);    // 8MB v transposed [B,H,DH,S]
  bf16* wqkvT = (bf16*)(ws + 40*MB);    // 6MB
  bf16* woutT = (bf16*)(ws + 46*MB);    // 2MB
  bf16* w1T   = (bf16*)(ws + 48*MB);    // 8MB
  bf16* w2T   = (bf16*)(ws + 56*MB);    // 8MB
  float* x2   = (float*)(ws + 64*MB);   // 16MB fp32 [M,D]
  bf16* xn2   = qb;                     // reuse (q dead after attention)
  bf16* hbuf  = (bf16*)(ws + 16*MB);    // 32MB [M,DFF]; reuses k,v,vT,wqkvT,woutT
  bf16* ao    = xn;

  dim3 blk(256);
  wtrans_kernel<<<dim3(3072/32, 1024/32), blk, 0, stream>>>(w_qkv, wqkvT, 1024, 3072);
  wtrans_kernel<<<dim3(1024/32, 1024/32), blk, 0, stream>>>(w_out, woutT, 1024, 1024);
  wtrans_kernel<<<dim3(4096/32, 1024/32), blk, 0, stream>>>(w1, w1T, 1024, 4096);
  wtrans_kernel<<<dim3(1024/32, 4096/32), blk, 0, stream>>>(w2, w2T, 4096, 1024);

  rmsnorm_kernel<<<dim3(M_), blk, 0, stream>>>(x, scale1, xn);

  gemm_kernel<0><<<dim3(3072/128, M_/128, 1), blk, 0, stream>>>(
      xn, wqkvT, b_qkv, qb, M_, 3072, 1024, 1024);

  vtrans_kernel<<<dim3(S_/32, DH_/32, B_*H_), blk, 0, stream>>>(vb, vT);

  attn_kernel<<<dim3(S_/64, H_, B_), blk, 0, stream>>>(qb, kb, vT, ao);

  // out-proj: x2 = x + b_out, then split-K=2 atomic GEMM adds ao @ w_out
  addbias_kernel<<<dim3(M_), blk, 0, stream>>>(x, b_out, x2);
  gemm_kernel<4><<<dim3(1024/128, M_/128, 2), blk, 0, stream>>>(
      ao, woutT, nullptr, x2, M_, 1024, 512, 1024);

  rmsnorm_kernel<<<dim3(M_), blk, 0, stream>>>(x2, scale2, xn2);

  gemm_kernel<2><<<dim3(4096/128, M_/128, 1), blk, 0, stream>>>(
      xn2, w1T, b1, hbuf, M_, 4096, 1024, 1024);

  // ffn2: d_out = x2 + b2, then split-K=4 atomic GEMM adds h @ w2
  addbias_kernel<<<dim3(M_), blk, 0, stream>>>(x2, b2, (float*)d_out);
  gemm_kernel<4><<<dim3(1024/128, M_/128, 4), blk, 0, stream>>>(
      hbuf, w2T, nullptr, d_out, M_, 1024, 1024, 4096);
}

// Round 4
// 424.951 us; speedup vs baseline: 1.2565x; 1.1399x over previous
//
#include <hip/hip_runtime.h>
#include <hip/hip_bf16.h>
#include <math.h>

#define B_ 2
#define S_ 2048
#define D_ 1024
#define H_ 16
#define DH_ 64
#define DFF_ 4096
#define M_ (B_*S_)

typedef __bf16 bf16;
typedef __bf16 bf16x8 __attribute__((ext_vector_type(8)));
typedef __bf16 bf16x4 __attribute__((ext_vector_type(4)));
typedef float f32x4 __attribute__((ext_vector_type(4)));

__device__ __forceinline__ void gll16(const void* g, void* l) {
  __builtin_amdgcn_global_load_lds(
      (const __attribute__((address_space(1))) void*)g,
      (__attribute__((address_space(3))) void*)l, 16, 0, 0);
}

// ---------------- RMSNorm: fp32 [rows, D] -> bf16 ----------------
__global__ __launch_bounds__(256) void rmsnorm_kernel(const float* __restrict__ x,
    const float* __restrict__ scale, bf16* __restrict__ out) {
  __shared__ float red[4];
  int row = blockIdx.x, t = threadIdx.x;
  const float4* xr = (const float4*)(x + (size_t)row * D_);
  float4 v = xr[t];
  float ss = v.x*v.x + v.y*v.y + v.z*v.z + v.w*v.w;
  #pragma unroll
  for (int off = 32; off > 0; off >>= 1) ss += __shfl_down(ss, off, 64);
  if ((t & 63) == 0) red[t >> 6] = ss;
  __syncthreads();
  float tot = red[0] + red[1] + red[2] + red[3];
  float r = rsqrtf(tot * (1.0f / D_) + 1e-8f);
  float4 sc = ((const float4*)scale)[t];
  bf16x4 o;
  o[0] = (bf16)(v.x * sc.x * r);
  o[1] = (bf16)(v.y * sc.y * r);
  o[2] = (bf16)(v.z * sc.z * r);
  o[3] = (bf16)(v.w * sc.w * r);
  *(bf16x4*)(out + (size_t)row * D_ + t * 4) = o;
}

// ---------- reduce_rms: x2 = x + bias + p0 + p1 ; xn2 = rmsnorm(x2)*scale ----------
__global__ __launch_bounds__(256) void reduce_rms_kernel(
    const bf16* __restrict__ p0, const bf16* __restrict__ p1,
    const float* __restrict__ x, const float* __restrict__ bias,
    const float* __restrict__ scale, float* __restrict__ x2, bf16* __restrict__ xn2) {
  __shared__ float red[4];
  int row = blockIdx.x, t = threadIdx.x;
  float4 xv = ((const float4*)(x + (size_t)row * D_))[t];
  float4 bv = ((const float4*)bias)[t];
  bf16x4 a = *(const bf16x4*)(p0 + (size_t)row * D_ + t * 4);
  bf16x4 b = *(const bf16x4*)(p1 + (size_t)row * D_ + t * 4);
  float s0 = xv.x + bv.x + (float)a[0] + (float)b[0];
  float s1 = xv.y + bv.y + (float)a[1] + (float)b[1];
  float s2 = xv.z + bv.z + (float)a[2] + (float)b[2];
  float s3 = xv.w + bv.w + (float)a[3] + (float)b[3];
  float4 o; o.x = s0; o.y = s1; o.z = s2; o.w = s3;
  ((float4*)(x2 + (size_t)row * D_))[t] = o;
  float ss = s0*s0 + s1*s1 + s2*s2 + s3*s3;
  #pragma unroll
  for (int off = 32; off > 0; off >>= 1) ss += __shfl_down(ss, off, 64);
  if ((t & 63) == 0) red[t >> 6] = ss;
  __syncthreads();
  float tot = red[0] + red[1] + red[2] + red[3];
  float r = rsqrtf(tot * (1.0f / D_) + 1e-8f);
  float4 sc = ((const float4*)scale)[t];
  bf16x4 on;
  on[0] = (bf16)(s0 * sc.x * r);
  on[1] = (bf16)(s1 * sc.y * r);
  on[2] = (bf16)(s2 * sc.z * r);
  on[3] = (bf16)(s3 * sc.w * r);
  *(bf16x4*)(xn2 + (size_t)row * D_ + t * 4) = on;
}

// ---------- reduce_out: dout = x2 + bias + p0 + p1 ----------
__global__ __launch_bounds__(256) void reduce_out_kernel(
    const bf16* __restrict__ p0, const bf16* __restrict__ p1,
    const float* __restrict__ x2, const float* __restrict__ bias,
    float* __restrict__ dout) {
  int row = blockIdx.x, t = threadIdx.x;
  float4 xv = ((const float4*)(x2 + (size_t)row * D_))[t];
  float4 bv = ((const float4*)bias)[t];
  bf16x4 a = *(const bf16x4*)(p0 + (size_t)row * D_ + t * 4);
  bf16x4 b = *(const bf16x4*)(p1 + (size_t)row * D_ + t * 4);
  float4 o;
  o.x = xv.x + bv.x + (float)a[0] + (float)b[0];
  o.y = xv.y + bv.y + (float)a[1] + (float)b[1];
  o.z = xv.z + bv.z + (float)a[2] + (float)b[2];
  o.w = xv.w + bv.w + (float)a[3] + (float)b[3];
  ((float4*)(dout + (size_t)row * D_))[t] = o;
}

// ---------------- Weight transpose: fp32 [K,N] -> bf16 [N,K] ----------------
__global__ __launch_bounds__(256) void wtrans_kernel(const float* __restrict__ W,
    bf16* __restrict__ Wt, int K, int N) {
  __shared__ float tile[32][33];
  int n0 = blockIdx.x * 32, k0 = blockIdx.y * 32;
  int tx = threadIdx.x & 31, ty = threadIdx.x >> 5;
  #pragma unroll
  for (int i = 0; i < 4; i++)
    tile[ty + i*8][tx] = W[(size_t)(k0 + ty + i*8) * N + n0 + tx];
  __syncthreads();
  #pragma unroll
  for (int i = 0; i < 4; i++)
    Wt[(size_t)(n0 + ty + i*8) * K + k0 + tx] = (bf16)tile[tx][ty + i*8];
}

// ---------------- V transpose: bf16 [B*H][S,DH] -> [B*H][DH,S] ----------------
__global__ __launch_bounds__(256) void vtrans_kernel(const bf16* __restrict__ Vin,
    bf16* __restrict__ Vt) {
  __shared__ bf16 tile[32][34];
  size_t base = (size_t)blockIdx.z * (S_ * DH_);
  int s0 = blockIdx.x * 32, d0 = blockIdx.y * 32;
  int tx = threadIdx.x & 31, ty = threadIdx.x >> 5;
  #pragma unroll
  for (int i = 0; i < 4; i++)
    tile[ty + i*8][tx] = Vin[base + (size_t)(s0 + ty + i*8) * DH_ + d0 + tx];
  __syncthreads();
  #pragma unroll
  for (int i = 0; i < 4; i++)
    Vt[base + (size_t)(d0 + ty + i*8) * S_ + s0 + tx] = tile[tx][ty + i*8];
}

__device__ __forceinline__ float gelu_exact(float v) {
  return 0.5f * v * (1.0f + erff(v * 0.70710678118654752f));
}

// ---------------- GEMM: C[M,N] = A[M,Ktot] @ Bt[N,Ktot]^T over k-slice ----------------
// MODE 0: qkv scatter to [3][B,H,S,DH] bf16 (+bias)
// MODE 2: bf16 out = gelu(acc + bias)   (ffn1)
// MODE 5: bf16 partial store (split-K): z=0 -> outp, z=1 -> outp2, no bias
template<int MODE>
__global__ __launch_bounds__(256) void gemm_kernel(
    const bf16* __restrict__ A, const bf16* __restrict__ Bt,
    const float* __restrict__ bias, void* __restrict__ outp, void* __restrict__ outp2,
    int M, int N, int K, int lda) {
  __shared__ __align__(16) bf16 As[128 * 32];
  __shared__ __align__(16) bf16 Bs[128 * 32];
  int t = threadIdx.x;
  int wave = t >> 6, lane = t & 63;
  int lm = lane & 15, lg = lane >> 4;
  int m0 = blockIdx.y * 128, n0 = blockIdx.x * 128;
  size_t koff = (size_t)blockIdx.z * K;
  int wm = (wave >> 1) * 64, wn = (wave & 1) * 64;
  f32x4 acc[4][4] = {};

  const bf16* Ag = A + (size_t)(m0 + (t >> 2)) * lda + koff + (t & 3) * 8;
  const bf16* Bg = Bt + (size_t)(n0 + (t >> 2)) * lda + koff + (t & 3) * 8;

  for (int k0 = 0; k0 < K; k0 += 32) {
    __syncthreads();
    gll16(Ag + k0, As + t * 8);
    gll16(Ag + k0 + (size_t)64 * lda, As + 2048 + t * 8);
    gll16(Bg + k0, Bs + t * 8);
    gll16(Bg + k0 + (size_t)64 * lda, Bs + 2048 + t * 8);
    __syncthreads();
    bf16x8 af[4], bfr[4];
    #pragma unroll
    for (int i = 0; i < 4; i++)
      af[i] = *(const bf16x8*)(As + (wm + i * 16 + lm) * 32 + lg * 8);
    #pragma unroll
    for (int j = 0; j < 4; j++)
      bfr[j] = *(const bf16x8*)(Bs + (wn + j * 16 + lm) * 32 + lg * 8);
    #pragma unroll
    for (int i = 0; i < 4; i++)
      #pragma unroll
      for (int j = 0; j < 4; j++)
        acc[i][j] = __builtin_amdgcn_mfma_f32_16x16x32_bf16(af[i], bfr[j], acc[i][j], 0, 0, 0);
  }

  bf16* pout = (MODE == 5) ? ((blockIdx.z == 0) ? (bf16*)outp : (bf16*)outp2) : (bf16*)outp;

  #pragma unroll
  for (int i = 0; i < 4; i++) {
    int row = m0 + wm + i * 16 + lg * 4;
    #pragma unroll
    for (int j = 0; j < 4; j++) {
      int col = n0 + wn + j * 16 + lm;
      float bcol = (MODE == 5) ? 0.f : bias[col];
      #pragma unroll
      for (int r = 0; r < 4; r++) {
        float v = acc[i][j][r] + bcol;
        int rr = row + r;
        if (MODE == 0) {
          int which = col >> 10, d = col & 1023;
          int hh = d >> 6, dh = d & 63;
          int bb = rr >> 11, s = rr & 2047;
          ((bf16*)outp)[(size_t)which * ((size_t)B_*H_*S_*DH_) +
              ((size_t)(bb * H_ + hh) * S_ + s) * DH_ + dh] = (bf16)v;
        } else if (MODE == 2) {
          ((bf16*)outp)[(size_t)rr * N + col] = (bf16)gelu_exact(v);
        } else {
          pout[(size_t)rr * N + col] = (bf16)v;
        }
      }
    }
  }
}

// ---------------- Flash attention v3 (fixed-max softmax, swizzled gll16) ----------------
#define PSTR 68
__global__ __launch_bounds__(256, 4) void attn_kernel(
    const bf16* __restrict__ q, const bf16* __restrict__ k,
    const bf16* __restrict__ vT, bf16* __restrict__ ao) {
  __shared__ __align__(16) bf16 Ks[64 * 64];
  __shared__ __align__(16) bf16 Vs[64 * 64];
  __shared__ __align__(16) bf16 Ps[4 * 16 * PSTR];
  int t = threadIdx.x, wave = t >> 6, lane = t & 63;
  int lm = lane & 15, lg = lane >> 4;
  int q0 = blockIdx.x * 64;
  int h = blockIdx.y, b = blockIdx.z;
  size_t base = (size_t)(b * H_ + h) * ((size_t)S_ * DH_);
  const bf16* Q = q + base;
  const bf16* K = k + base;
  const bf16* V = vT + base;   // [DH][S]
  const float LOG2E = 1.4426950408889634f;
  float nslope = -exp2f(-0.5f * (float)(h + 1)) * LOG2E;
  const float qscale = 0.125f * LOG2E;
  const float FMAX = 8.0f;

  bf16x8 qf[2];
  #pragma unroll
  for (int h2 = 0; h2 < 2; h2++) {
    bf16x8 v = *(const bf16x8*)(Q + (size_t)(q0 + wave * 16 + lm) * DH_ + h2 * 32 + lg * 8);
    #pragma unroll
    for (int e = 0; e < 8; e++) v[e] = (bf16)((float)v[e] * qscale);
    qf[h2] = v;
  }

  int row0 = t >> 3, jslot = t & 7;
  int gsw = (jslot ^ (row0 & 7)) << 3;
  const bf16* Ksrc0 = K + (size_t)row0 * DH_ + gsw;
  const bf16* Vsrc0 = V + (size_t)row0 * S_ + gsw;

  f32x4 oacc[4] = {};
  float rs[4] = {0.f, 0.f, 0.f, 0.f};
  int psw = lm & 7;

  for (int jt = 0; jt < S_; jt += 64) {
    __syncthreads();
    gll16(Ksrc0 + (size_t)jt * DH_, Ks + (size_t)t * 8);
    gll16(Ksrc0 + (size_t)(jt + 32) * DH_, Ks + (size_t)(t + 256) * 8);
    gll16(Vsrc0 + jt, Vs + (size_t)t * 8);
    gll16(Vsrc0 + (size_t)32 * S_ + jt, Vs + (size_t)(t + 256) * 8);
    __syncthreads();

    f32x4 sc[4];
    #pragma unroll
    for (int tt = 0; tt < 4; tt++) {
      f32x4 a = {-FMAX, -FMAX, -FMAX, -FMAX};
      int krow = tt * 16 + lm;
      bf16x8 kb0 = *(const bf16x8*)(Ks + (size_t)(krow * 8 + (lg ^ psw)) * 8);
      bf16x8 kb1 = *(const bf16x8*)(Ks + (size_t)(krow * 8 + ((lg + 4) ^ psw)) * 8);
      a = __builtin_amdgcn_mfma_f32_16x16x32_bf16(qf[0], kb0, a, 0, 0, 0);
      a = __builtin_amdgcn_mfma_f32_16x16x32_bf16(qf[1], kb1, a, 0, 0, 0);
      sc[tt] = a;
    }

    bf16* Pw = Ps + wave * (16 * PSTR);
    int i0 = q0 + wave * 16 + lg * 4;
    #pragma unroll
    for (int tt = 0; tt < 4; tt++) {
      float f0 = (float)(i0 - jt - tt * 16 - lm);
      #pragma unroll
      for (int r = 0; r < 4; r++) {
        float s2 = fmaf(nslope, fabsf(f0 + (float)r), sc[tt][r]);
        float p = __builtin_amdgcn_exp2f(s2);
        rs[r] += p;
        Pw[(lg * 4 + r) * PSTR + tt * 16 + lm] = (bf16)p;
      }
    }

    bf16x8 ap0 = *(const bf16x8*)(Pw + lm * PSTR + lg * 8);
    bf16x8 ap1 = *(const bf16x8*)(Pw + lm * PSTR + 32 + lg * 8);
    #pragma unroll
    for (int tt = 0; tt < 4; tt++) {
      int vrow = tt * 16 + lm;
      bf16x8 vb0 = *(const bf16x8*)(Vs + (size_t)(vrow * 8 + (lg ^ psw)) * 8);
      bf16x8 vb1 = *(const bf16x8*)(Vs + (size_t)(vrow * 8 + ((lg + 4) ^ psw)) * 8);
      oacc[tt] = __builtin_amdgcn_mfma_f32_16x16x32_bf16(ap0, vb0, oacc[tt], 0, 0, 0);
      oacc[tt] = __builtin_amdgcn_mfma_f32_16x16x32_bf16(ap1, vb1, oacc[tt], 0, 0, 0);
    }
  }

  #pragma unroll
  for (int r = 0; r < 4; r++) {
    #pragma unroll
    for (int off = 1; off < 16; off <<= 1)
      rs[r] += __shfl_xor(rs[r], off, 16);
  }

  #pragma unroll
  for (int r = 0; r < 4; r++) {
    float inv = 1.0f / rs[r];
    int row = q0 + wave * 16 + lg * 4 + r;
    #pragma unroll
    for (int tt = 0; tt < 4; tt++) {
      int col = h * 64 + tt * 16 + lm;
      ao[((size_t)(b * S_) + row) * D_ + col] = (bf16)(oacc[tt][r] * inv);
    }
  }
}

extern "C" void kernel_launch(void* const* d_in, const int* in_sizes, int n_in,
                              void* d_out, int out_size, void* d_ws, size_t ws_size,
                              hipStream_t stream) {
  const float* x      = (const float*)d_in[0];
  const float* scale1 = (const float*)d_in[1];
  const float* scale2 = (const float*)d_in[2];
  const float* w_qkv  = (const float*)d_in[3];
  const float* b_qkv  = (const float*)d_in[4];
  const float* w_out  = (const float*)d_in[5];
  const float* b_out  = (const float*)d_in[6];
  const float* w1     = (const float*)d_in[7];
  const float* b1     = (const float*)d_in[8];
  const float* w2     = (const float*)d_in[9];
  const float* b2     = (const float*)d_in[10];

  char* ws = (char*)d_ws;
  const size_t MB = 1024 * 1024;
  // layout (80 MB):
  bf16* xn    = (bf16*)(ws + 0);        // 0-8:   xn -> ao -> ffn2 partial 0
  bf16* qb    = (bf16*)(ws + 8*MB);     // 8-16:  q -> xn2
  bf16* kb    = (bf16*)(ws + 16*MB);    // 16-24: k -> out-proj partial 0 -> hbuf[0:8]
  bf16* vb    = (bf16*)(ws + 24*MB);    // 24-32: v -> out-proj partial 1 -> hbuf[8:16]
  bf16* vT    = (bf16*)(ws + 32*MB);    // 32-40: vT -> hbuf[16:24]
  bf16* wqkvT = (bf16*)(ws + 40*MB);    // 40-46: wqkvT -> hbuf[24:30]
  bf16* woutT = (bf16*)(ws + 46*MB);    // 46-48: woutT -> hbuf[30:32]
  bf16* w1T   = (bf16*)(ws + 48*MB);    // 48-56: w1T -> ffn2 partial 1
  bf16* w2T   = (bf16*)(ws + 56*MB);    // 56-64: w2T
  float* x2   = (float*)(ws + 64*MB);   // 64-80: x2 fp32
  bf16* xn2   = qb;
  bf16* pp0   = kb;                     // out-proj partials
  bf16* pp1   = vb;
  bf16* hbuf  = kb;                     // 16-48 [M,DFF]
  bf16* qp0   = xn;                     // ffn2 partials
  bf16* qp1   = w1T;
  bf16* ao    = xn;

  dim3 blk(256);
  wtrans_kernel<<<dim3(3072/32, 1024/32), blk, 0, stream>>>(w_qkv, wqkvT, 1024, 3072);
  wtrans_kernel<<<dim3(1024/32, 1024/32), blk, 0, stream>>>(w_out, woutT, 1024, 1024);
  wtrans_kernel<<<dim3(4096/32, 1024/32), blk, 0, stream>>>(w1, w1T, 1024, 4096);
  wtrans_kernel<<<dim3(1024/32, 4096/32), blk, 0, stream>>>(w2, w2T, 4096, 1024);

  rmsnorm_kernel<<<dim3(M_), blk, 0, stream>>>(x, scale1, xn);

  gemm_kernel<0><<<dim3(3072/128, M_/128, 1), blk, 0, stream>>>(
      xn, wqkvT, b_qkv, qb, nullptr, M_, 3072, 1024, 1024);

  vtrans_kernel<<<dim3(S_/32, DH_/32, B_*H_), blk, 0, stream>>>(vb, vT);

  attn_kernel<<<dim3(S_/64, H_, B_), blk, 0, stream>>>(qb, kb, vT, ao);

  // out-proj split-K=2: bf16 partials, then fused reduce+residual+bias+rmsnorm
  gemm_kernel<5><<<dim3(1024/128, M_/128, 2), blk, 0, stream>>>(
      ao, woutT, nullptr, pp0, pp1, M_, 1024, 512, 1024);
  reduce_rms_kernel<<<dim3(M_), blk, 0, stream>>>(pp0, pp1, x, b_out, scale2, x2, xn2);

  gemm_kernel<2><<<dim3(4096/128, M_/128, 1), blk, 0, stream>>>(
      xn2, w1T, b1, hbuf, nullptr, M_, 4096, 1024, 1024);

  // ffn2 split-K=2: bf16 partials, then fused reduce+residual+bias -> d_out
  gemm_kernel<5><<<dim3(1024/128, M_/128, 2), blk, 0, stream>>>(
      hbuf, w2T, nullptr, qp0, qp1, M_, 1024, 2048, 4096);
  reduce_out_kernel<<<dim3(M_), blk, 0, stream>>>(qp0, qp1, x2, b2, (float*)d_out);
}

// Round 5
// 412.739 us; speedup vs baseline: 1.2937x; 1.0296x over previous
//
#include <hip/hip_runtime.h>
#include <hip/hip_bf16.h>
#include <math.h>

#define B_ 2
#define S_ 2048
#define D_ 1024
#define H_ 16
#define DH_ 64
#define DFF_ 4096
#define M_ (B_*S_)

typedef __bf16 bf16;
typedef __bf16 bf16x8 __attribute__((ext_vector_type(8)));
typedef __bf16 bf16x4 __attribute__((ext_vector_type(4)));
typedef float f32x4 __attribute__((ext_vector_type(4)));

__device__ __forceinline__ void gll16(const void* g, void* l) {
  __builtin_amdgcn_global_load_lds(
      (const __attribute__((address_space(1))) void*)g,
      (__attribute__((address_space(3))) void*)l, 16, 0, 0);
}

// ---------------- RMSNorm: fp32 [rows, D] -> bf16 ----------------
__global__ __launch_bounds__(256) void rmsnorm_kernel(const float* __restrict__ x,
    const float* __restrict__ scale, bf16* __restrict__ out) {
  __shared__ float red[4];
  int row = blockIdx.x, t = threadIdx.x;
  const float4* xr = (const float4*)(x + (size_t)row * D_);
  float4 v = xr[t];
  float ss = v.x*v.x + v.y*v.y + v.z*v.z + v.w*v.w;
  #pragma unroll
  for (int off = 32; off > 0; off >>= 1) ss += __shfl_down(ss, off, 64);
  if ((t & 63) == 0) red[t >> 6] = ss;
  __syncthreads();
  float tot = red[0] + red[1] + red[2] + red[3];
  float r = rsqrtf(tot * (1.0f / D_) + 1e-8f);
  float4 sc = ((const float4*)scale)[t];
  bf16x4 o;
  o[0] = (bf16)(v.x * sc.x * r);
  o[1] = (bf16)(v.y * sc.y * r);
  o[2] = (bf16)(v.z * sc.z * r);
  o[3] = (bf16)(v.w * sc.w * r);
  *(bf16x4*)(out + (size_t)row * D_ + t * 4) = o;
}

// ---------- reduce_rms: x2 = x + bias + p0 + p1 ; xn2 = rmsnorm(x2)*scale ----------
__global__ __launch_bounds__(256) void reduce_rms_kernel(
    const bf16* __restrict__ p0, const bf16* __restrict__ p1,
    const float* __restrict__ x, const float* __restrict__ bias,
    const float* __restrict__ scale, float* __restrict__ x2, bf16* __restrict__ xn2) {
  __shared__ float red[4];
  int row = blockIdx.x, t = threadIdx.x;
  float4 xv = ((const float4*)(x + (size_t)row * D_))[t];
  float4 bv = ((const float4*)bias)[t];
  bf16x4 a = *(const bf16x4*)(p0 + (size_t)row * D_ + t * 4);
  bf16x4 b = *(const bf16x4*)(p1 + (size_t)row * D_ + t * 4);
  float s0 = xv.x + bv.x + (float)a[0] + (float)b[0];
  float s1 = xv.y + bv.y + (float)a[1] + (float)b[1];
  float s2 = xv.z + bv.z + (float)a[2] + (float)b[2];
  float s3 = xv.w + bv.w + (float)a[3] + (float)b[3];
  float4 o; o.x = s0; o.y = s1; o.z = s2; o.w = s3;
  ((float4*)(x2 + (size_t)row * D_))[t] = o;
  float ss = s0*s0 + s1*s1 + s2*s2 + s3*s3;
  #pragma unroll
  for (int off = 32; off > 0; off >>= 1) ss += __shfl_down(ss, off, 64);
  if ((t & 63) == 0) red[t >> 6] = ss;
  __syncthreads();
  float tot = red[0] + red[1] + red[2] + red[3];
  float r = rsqrtf(tot * (1.0f / D_) + 1e-8f);
  float4 sc = ((const float4*)scale)[t];
  bf16x4 on;
  on[0] = (bf16)(s0 * sc.x * r);
  on[1] = (bf16)(s1 * sc.y * r);
  on[2] = (bf16)(s2 * sc.z * r);
  on[3] = (bf16)(s3 * sc.w * r);
  *(bf16x4*)(xn2 + (size_t)row * D_ + t * 4) = on;
}

// ---------- reduce_out: dout = x2 + bias + p0 + p1 ----------
__global__ __launch_bounds__(256) void reduce_out_kernel(
    const bf16* __restrict__ p0, const bf16* __restrict__ p1,
    const float* __restrict__ x2, const float* __restrict__ bias,
    float* __restrict__ dout) {
  int row = blockIdx.x, t = threadIdx.x;
  float4 xv = ((const float4*)(x2 + (size_t)row * D_))[t];
  float4 bv = ((const float4*)bias)[t];
  bf16x4 a = *(const bf16x4*)(p0 + (size_t)row * D_ + t * 4);
  bf16x4 b = *(const bf16x4*)(p1 + (size_t)row * D_ + t * 4);
  float4 o;
  o.x = xv.x + bv.x + (float)a[0] + (float)b[0];
  o.y = xv.y + bv.y + (float)a[1] + (float)b[1];
  o.z = xv.z + bv.z + (float)a[2] + (float)b[2];
  o.w = xv.w + bv.w + (float)a[3] + (float)b[3];
  ((float4*)(dout + (size_t)row * D_))[t] = o;
}

// ---------------- Weight transpose: fp32 [K,N] -> bf16 [N,K] ----------------
__global__ __launch_bounds__(256) void wtrans_kernel(const float* __restrict__ W,
    bf16* __restrict__ Wt, int K, int N) {
  __shared__ float tile[32][33];
  int n0 = blockIdx.x * 32, k0 = blockIdx.y * 32;
  int tx = threadIdx.x & 31, ty = threadIdx.x >> 5;
  #pragma unroll
  for (int i = 0; i < 4; i++)
    tile[ty + i*8][tx] = W[(size_t)(k0 + ty + i*8) * N + n0 + tx];
  __syncthreads();
  #pragma unroll
  for (int i = 0; i < 4; i++)
    Wt[(size_t)(n0 + ty + i*8) * K + k0 + tx] = (bf16)tile[tx][ty + i*8];
}

// ---------------- V transpose: bf16 [B*H][S,DH] -> [B*H][DH,S] ----------------
__global__ __launch_bounds__(256) void vtrans_kernel(const bf16* __restrict__ Vin,
    bf16* __restrict__ Vt) {
  __shared__ bf16 tile[32][34];
  size_t base = (size_t)blockIdx.z * (S_ * DH_);
  int s0 = blockIdx.x * 32, d0 = blockIdx.y * 32;
  int tx = threadIdx.x & 31, ty = threadIdx.x >> 5;
  #pragma unroll
  for (int i = 0; i < 4; i++)
    tile[ty + i*8][tx] = Vin[base + (size_t)(s0 + ty + i*8) * DH_ + d0 + tx];
  __syncthreads();
  #pragma unroll
  for (int i = 0; i < 4; i++)
    Vt[base + (size_t)(d0 + ty + i*8) * S_ + s0 + tx] = tile[tx][ty + i*8];
}

__device__ __forceinline__ float gelu_exact(float v) {
  return 0.5f * v * (1.0f + erff(v * 0.70710678118654752f));
}

// ---------------- GEMM: C[M,N] = A[M,Ktot] @ Bt[N,Ktot]^T over k-slice ----------------
// MODE 0: qkv scatter to [3][B,H,S,DH] bf16 (+bias)
// MODE 2: bf16 out = gelu(acc + bias)   (ffn1)
// MODE 5: bf16 partial store (split-K): z=0 -> outp, z=1 -> outp2, no bias
template<int MODE>
__global__ __launch_bounds__(256) void gemm_kernel(
    const bf16* __restrict__ A, const bf16* __restrict__ Bt,
    const float* __restrict__ bias, void* __restrict__ outp, void* __restrict__ outp2,
    int M, int N, int K, int lda) {
  __shared__ __align__(16) bf16 As[128 * 32];
  __shared__ __align__(16) bf16 Bs[128 * 32];
  int t = threadIdx.x;
  int wave = t >> 6, lane = t & 63;
  int lm = lane & 15, lg = lane >> 4;
  int m0 = blockIdx.y * 128, n0 = blockIdx.x * 128;
  size_t koff = (size_t)blockIdx.z * K;
  int wm = (wave >> 1) * 64, wn = (wave & 1) * 64;
  f32x4 acc[4][4] = {};

  const bf16* Ag = A + (size_t)(m0 + (t >> 2)) * lda + koff + (t & 3) * 8;
  const bf16* Bg = Bt + (size_t)(n0 + (t >> 2)) * lda + koff + (t & 3) * 8;

  for (int k0 = 0; k0 < K; k0 += 32) {
    __syncthreads();
    gll16(Ag + k0, As + t * 8);
    gll16(Ag + k0 + (size_t)64 * lda, As + 2048 + t * 8);
    gll16(Bg + k0, Bs + t * 8);
    gll16(Bg + k0 + (size_t)64 * lda, Bs + 2048 + t * 8);
    __syncthreads();
    bf16x8 af[4], bfr[4];
    #pragma unroll
    for (int i = 0; i < 4; i++)
      af[i] = *(const bf16x8*)(As + (wm + i * 16 + lm) * 32 + lg * 8);
    #pragma unroll
    for (int j = 0; j < 4; j++)
      bfr[j] = *(const bf16x8*)(Bs + (wn + j * 16 + lm) * 32 + lg * 8);
    #pragma unroll
    for (int i = 0; i < 4; i++)
      #pragma unroll
      for (int j = 0; j < 4; j++)
        acc[i][j] = __builtin_amdgcn_mfma_f32_16x16x32_bf16(af[i], bfr[j], acc[i][j], 0, 0, 0);
  }

  bf16* pout = (MODE == 5) ? ((blockIdx.z == 0) ? (bf16*)outp : (bf16*)outp2) : (bf16*)outp;

  #pragma unroll
  for (int i = 0; i < 4; i++) {
    int row = m0 + wm + i * 16 + lg * 4;
    #pragma unroll
    for (int j = 0; j < 4; j++) {
      int col = n0 + wn + j * 16 + lm;
      float bcol = (MODE == 5) ? 0.f : bias[col];
      #pragma unroll
      for (int r = 0; r < 4; r++) {
        float v = acc[i][j][r] + bcol;
        int rr = row + r;
        if (MODE == 0) {
          int which = col >> 10, d = col & 1023;
          int hh = d >> 6, dh = d & 63;
          int bb = rr >> 11, s = rr & 2047;
          ((bf16*)outp)[(size_t)which * ((size_t)B_*H_*S_*DH_) +
              ((size_t)(bb * H_ + hh) * S_ + s) * DH_ + dh] = (bf16)v;
        } else if (MODE == 2) {
          ((bf16*)outp)[(size_t)rr * N + col] = (bf16)gelu_exact(v);
        } else {
          pout[(size_t)rr * N + col] = (bf16)v;
        }
      }
    }
  }
}

// ---------------- Flash attention v4 ----------------
// Fixed-max softmax, swizzled gll16 staging, ALiBi banding (skip far tiles),
// K/V double-buffer with ONE barrier per tile (loads for j+1 issued right
// after the barrier releasing tile j; drained by the next barrier).
#define PSTR 68
__global__ __launch_bounds__(256, 3) void attn_kernel(
    const bf16* __restrict__ q, const bf16* __restrict__ k,
    const bf16* __restrict__ vT, bf16* __restrict__ ao) {
  __shared__ __align__(16) bf16 Ks[2][64 * 64];
  __shared__ __align__(16) bf16 Vs[2][64 * 64];
  __shared__ __align__(16) bf16 Ps[4 * 16 * PSTR];
  int t = threadIdx.x, wave = t >> 6, lane = t & 63;
  int lm = lane & 15, lg = lane >> 4;
  int q0 = blockIdx.x * 64;
  int h = blockIdx.y, b = blockIdx.z;
  size_t base = (size_t)(b * H_ + h) * ((size_t)S_ * DH_);
  const bf16* Q = q + base;
  const bf16* K = k + base;
  const bf16* V = vT + base;   // [DH][S]
  const float LOG2E = 1.4426950408889634f;
  float sl2 = exp2f(-0.5f * (float)(h + 1)) * LOG2E;   // ALiBi slope, log2/pos
  float nslope = -sl2;
  const float qscale = 0.125f * LOG2E;
  const float FMAX = 8.0f;

  // ALiBi band: tiles with min|i-j| > 24/sl2 have p < 2^-29 -> skip.
  int W = (int)(24.0f / sl2);
  int jlo = (q0 - W) >> 6; if (jlo < 0) jlo = 0;
  int jhi = ((q0 + 63 + W) >> 6) + 1; if (jhi > S_ / 64) jhi = S_ / 64;

  bf16x8 qf[2];
  #pragma unroll
  for (int h2 = 0; h2 < 2; h2++) {
    bf16x8 v = *(const bf16x8*)(Q + (size_t)(q0 + wave * 16 + lm) * DH_ + h2 * 32 + lg * 8);
    #pragma unroll
    for (int e = 0; e < 8; e++) v[e] = (bf16)((float)v[e] * qscale);
    qf[h2] = v;
  }

  int row0 = t >> 3, jslot = t & 7;
  int gsw = (jslot ^ (row0 & 7)) << 3;
  const bf16* Ksrc0 = K + (size_t)row0 * DH_ + gsw;
  const bf16* Vsrc0 = V + (size_t)row0 * S_ + gsw;

  // prologue: stage first tile into buffer 0
  {
    int jt = jlo << 6;
    gll16(Ksrc0 + (size_t)jt * DH_, Ks[0] + (size_t)t * 8);
    gll16(Ksrc0 + (size_t)(jt + 32) * DH_, Ks[0] + (size_t)(t + 256) * 8);
    gll16(Vsrc0 + jt, Vs[0] + (size_t)t * 8);
    gll16(Vsrc0 + (size_t)32 * S_ + jt, Vs[0] + (size_t)(t + 256) * 8);
  }

  f32x4 oacc[4] = {};
  float rs[4] = {0.f, 0.f, 0.f, 0.f};
  int psw = lm & 7;

  for (int jj = jlo; jj < jhi; ++jj) {
    int buf = (jj - jlo) & 1;
    int jt = jj << 6;
    __syncthreads();   // drains vmcnt(0): tile jj ready; prior readers of buf^1 done
    if (jj + 1 < jhi) {
      int jn = (jj + 1) << 6;
      gll16(Ksrc0 + (size_t)jn * DH_, Ks[buf ^ 1] + (size_t)t * 8);
      gll16(Ksrc0 + (size_t)(jn + 32) * DH_, Ks[buf ^ 1] + (size_t)(t + 256) * 8);
      gll16(Vsrc0 + jn, Vs[buf ^ 1] + (size_t)t * 8);
      gll16(Vsrc0 + (size_t)32 * S_ + jn, Vs[buf ^ 1] + (size_t)(t + 256) * 8);
    }
    const bf16* Kb = Ks[buf];
    const bf16* Vb = Vs[buf];

    f32x4 sc[4];
    #pragma unroll
    for (int tt = 0; tt < 4; tt++) {
      f32x4 a = {-FMAX, -FMAX, -FMAX, -FMAX};
      int krow = tt * 16 + lm;
      bf16x8 kb0 = *(const bf16x8*)(Kb + (size_t)(krow * 8 + (lg ^ psw)) * 8);
      bf16x8 kb1 = *(const bf16x8*)(Kb + (size_t)(krow * 8 + ((lg + 4) ^ psw)) * 8);
      a = __builtin_amdgcn_mfma_f32_16x16x32_bf16(qf[0], kb0, a, 0, 0, 0);
      a = __builtin_amdgcn_mfma_f32_16x16x32_bf16(qf[1], kb1, a, 0, 0, 0);
      sc[tt] = a;
    }

    bf16* Pw = Ps + wave * (16 * PSTR);   // per-wave private: no barrier needed
    int i0 = q0 + wave * 16 + lg * 4;
    #pragma unroll
    for (int tt = 0; tt < 4; tt++) {
      float f0 = (float)(i0 - jt - tt * 16 - lm);
      #pragma unroll
      for (int r = 0; r < 4; r++) {
        float s2 = fmaf(nslope, fabsf(f0 + (float)r), sc[tt][r]);
        float p = __builtin_amdgcn_exp2f(s2);
        rs[r] += p;
        Pw[(lg * 4 + r) * PSTR + tt * 16 + lm] = (bf16)p;
      }
    }

    bf16x8 ap0 = *(const bf16x8*)(Pw + lm * PSTR + lg * 8);
    bf16x8 ap1 = *(const bf16x8*)(Pw + lm * PSTR + 32 + lg * 8);
    #pragma unroll
    for (int tt = 0; tt < 4; tt++) {
      int vrow = tt * 16 + lm;
      bf16x8 vb0 = *(const bf16x8*)(Vb + (size_t)(vrow * 8 + (lg ^ psw)) * 8);
      bf16x8 vb1 = *(const bf16x8*)(Vb + (size_t)(vrow * 8 + ((lg + 4) ^ psw)) * 8);
      oacc[tt] = __builtin_amdgcn_mfma_f32_16x16x32_bf16(ap0, vb0, oacc[tt], 0, 0, 0);
      oacc[tt] = __builtin_amdgcn_mfma_f32_16x16x32_bf16(ap1, vb1, oacc[tt], 0, 0, 0);
    }
  }

  #pragma unroll
  for (int r = 0; r < 4; r++) {
    #pragma unroll
    for (int off = 1; off < 16; off <<= 1)
      rs[r] += __shfl_xor(rs[r], off, 16);
  }

  #pragma unroll
  for (int r = 0; r < 4; r++) {
    float inv = 1.0f / rs[r];
    int row = q0 + wave * 16 + lg * 4 + r;
    #pragma unroll
    for (int tt = 0; tt < 4; tt++) {
      int col = h * 64 + tt * 16 + lm;
      ao[((size_t)(b * S_) + row) * D_ + col] = (bf16)(oacc[tt][r] * inv);
    }
  }
}

extern "C" void kernel_launch(void* const* d_in, const int* in_sizes, int n_in,
                              void* d_out, int out_size, void* d_ws, size_t ws_size,
                              hipStream_t stream) {
  const float* x      = (const float*)d_in[0];
  const float* scale1 = (const float*)d_in[1];
  const float* scale2 = (const float*)d_in[2];
  const float* w_qkv  = (const float*)d_in[3];
  const float* b_qkv  = (const float*)d_in[4];
  const float* w_out  = (const float*)d_in[5];
  const float* b_out  = (const float*)d_in[6];
  const float* w1     = (const float*)d_in[7];
  const float* b1     = (const float*)d_in[8];
  const float* w2     = (const float*)d_in[9];
  const float* b2     = (const float*)d_in[10];

  char* ws = (char*)d_ws;
  const size_t MB = 1024 * 1024;
  // layout (80 MB):
  bf16* xn    = (bf16*)(ws + 0);        // 0-8:   xn -> ao -> ffn2 partial 0
  bf16* qb    = (bf16*)(ws + 8*MB);     // 8-16:  q -> xn2
  bf16* kb    = (bf16*)(ws + 16*MB);    // 16-24: k -> out-proj partial 0 -> hbuf[0:8]
  bf16* vb    = (bf16*)(ws + 24*MB);    // 24-32: v -> out-proj partial 1 -> hbuf[8:16]
  bf16* vT    = (bf16*)(ws + 32*MB);    // 32-40: vT -> hbuf[16:24]
  bf16* wqkvT = (bf16*)(ws + 40*MB);    // 40-46: wqkvT -> hbuf[24:30]
  bf16* woutT = (bf16*)(ws + 46*MB);    // 46-48: woutT -> hbuf[30:32]
  bf16* w1T   = (bf16*)(ws + 48*MB);    // 48-56: w1T -> ffn2 partial 1
  bf16* w2T   = (bf16*)(ws + 56*MB);    // 56-64: w2T
  float* x2   = (float*)(ws + 64*MB);   // 64-80: x2 fp32
  bf16* xn2   = qb;
  bf16* pp0   = kb;                     // out-proj partials
  bf16* pp1   = vb;
  bf16* hbuf  = kb;                     // 16-48 [M,DFF]
  bf16* qp0   = xn;                     // ffn2 partials
  bf16* qp1   = w1T;
  bf16* ao    = xn;

  dim3 blk(256);
  wtrans_kernel<<<dim3(3072/32, 1024/32), blk, 0, stream>>>(w_qkv, wqkvT, 1024, 3072);
  wtrans_kernel<<<dim3(1024/32, 1024/32), blk, 0, stream>>>(w_out, woutT, 1024, 1024);
  wtrans_kernel<<<dim3(4096/32, 1024/32), blk, 0, stream>>>(w1, w1T, 1024, 4096);
  wtrans_kernel<<<dim3(1024/32, 4096/32), blk, 0, stream>>>(w2, w2T, 4096, 1024);

  rmsnorm_kernel<<<dim3(M_), blk, 0, stream>>>(x, scale1, xn);

  gemm_kernel<0><<<dim3(3072/128, M_/128, 1), blk, 0, stream>>>(
      xn, wqkvT, b_qkv, qb, nullptr, M_, 3072, 1024, 1024);

  vtrans_kernel<<<dim3(S_/32, DH_/32, B_*H_), blk, 0, stream>>>(vb, vT);

  attn_kernel<<<dim3(S_/64, H_, B_), blk, 0, stream>>>(qb, kb, vT, ao);

  // out-proj split-K=2: bf16 partials, then fused reduce+residual+bias+rmsnorm
  gemm_kernel<5><<<dim3(1024/128, M_/128, 2), blk, 0, stream>>>(
      ao, woutT, nullptr, pp0, pp1, M_, 1024, 512, 1024);
  reduce_rms_kernel<<<dim3(M_), blk, 0, stream>>>(pp0, pp1, x, b_out, scale2, x2, xn2);

  gemm_kernel<2><<<dim3(4096/128, M_/128, 1), blk, 0, stream>>>(
      xn2, w1T, b1, hbuf, nullptr, M_, 4096, 1024, 1024);

  // ffn2 split-K=2: bf16 partials, then fused reduce+residual+bias -> d_out
  gemm_kernel<5><<<dim3(1024/128, M_/128, 2), blk, 0, stream>>>(
      hbuf, w2T, nullptr, qp0, qp1, M_, 1024, 2048, 4096);
  reduce_out_kernel<<<dim3(M_), blk, 0, stream>>>(qp0, qp1, x2, b2, (float*)d_out);
}

// Round 6
// 377.723 us; speedup vs baseline: 1.4136x; 1.0927x over previous
//
#include <hip/hip_runtime.h>
#include <hip/hip_bf16.h>
#include <math.h>

#define B_ 2
#define S_ 2048
#define D_ 1024
#define H_ 16
#define DH_ 64
#define DFF_ 4096
#define M_ (B_*S_)

typedef __bf16 bf16;
typedef __bf16 bf16x8 __attribute__((ext_vector_type(8)));
typedef __bf16 bf16x4 __attribute__((ext_vector_type(4)));
typedef float f32x4 __attribute__((ext_vector_type(4)));

__device__ __forceinline__ void gll16(const void* g, void* l) {
  __builtin_amdgcn_global_load_lds(
      (const __attribute__((address_space(1))) void*)g,
      (__attribute__((address_space(3))) void*)l, 16, 0, 0);
}

// ---------------- RMSNorm: fp32 [rows, D] -> bf16 ----------------
__global__ __launch_bounds__(256) void rmsnorm_kernel(const float* __restrict__ x,
    const float* __restrict__ scale, bf16* __restrict__ out) {
  __shared__ float red[4];
  int row = blockIdx.x, t = threadIdx.x;
  const float4* xr = (const float4*)(x + (size_t)row * D_);
  float4 v = xr[t];
  float ss = v.x*v.x + v.y*v.y + v.z*v.z + v.w*v.w;
  #pragma unroll
  for (int off = 32; off > 0; off >>= 1) ss += __shfl_down(ss, off, 64);
  if ((t & 63) == 0) red[t >> 6] = ss;
  __syncthreads();
  float tot = red[0] + red[1] + red[2] + red[3];
  float r = rsqrtf(tot * (1.0f / D_) + 1e-8f);
  float4 sc = ((const float4*)scale)[t];
  bf16x4 o;
  o[0] = (bf16)(v.x * sc.x * r);
  o[1] = (bf16)(v.y * sc.y * r);
  o[2] = (bf16)(v.z * sc.z * r);
  o[3] = (bf16)(v.w * sc.w * r);
  *(bf16x4*)(out + (size_t)row * D_ + t * 4) = o;
}

// ---------- reduce_rms: x2 = x + bias + p0 + p1 ; xn2 = rmsnorm(x2)*scale ----------
__global__ __launch_bounds__(256) void reduce_rms_kernel(
    const bf16* __restrict__ p0, const bf16* __restrict__ p1,
    const float* __restrict__ x, const float* __restrict__ bias,
    const float* __restrict__ scale, float* __restrict__ x2, bf16* __restrict__ xn2) {
  __shared__ float red[4];
  int row = blockIdx.x, t = threadIdx.x;
  float4 xv = ((const float4*)(x + (size_t)row * D_))[t];
  float4 bv = ((const float4*)bias)[t];
  bf16x4 a = *(const bf16x4*)(p0 + (size_t)row * D_ + t * 4);
  bf16x4 b = *(const bf16x4*)(p1 + (size_t)row * D_ + t * 4);
  float s0 = xv.x + bv.x + (float)a[0] + (float)b[0];
  float s1 = xv.y + bv.y + (float)a[1] + (float)b[1];
  float s2 = xv.z + bv.z + (float)a[2] + (float)b[2];
  float s3 = xv.w + bv.w + (float)a[3] + (float)b[3];
  float4 o; o.x = s0; o.y = s1; o.z = s2; o.w = s3;
  ((float4*)(x2 + (size_t)row * D_))[t] = o;
  float ss = s0*s0 + s1*s1 + s2*s2 + s3*s3;
  #pragma unroll
  for (int off = 32; off > 0; off >>= 1) ss += __shfl_down(ss, off, 64);
  if ((t & 63) == 0) red[t >> 6] = ss;
  __syncthreads();
  float tot = red[0] + red[1] + red[2] + red[3];
  float r = rsqrtf(tot * (1.0f / D_) + 1e-8f);
  float4 sc = ((const float4*)scale)[t];
  bf16x4 on;
  on[0] = (bf16)(s0 * sc.x * r);
  on[1] = (bf16)(s1 * sc.y * r);
  on[2] = (bf16)(s2 * sc.z * r);
  on[3] = (bf16)(s3 * sc.w * r);
  *(bf16x4*)(xn2 + (size_t)row * D_ + t * 4) = on;
}

// ---------- reduce_out: dout = x2 + bias + p0 + p1 ----------
__global__ __launch_bounds__(256) void reduce_out_kernel(
    const bf16* __restrict__ p0, const bf16* __restrict__ p1,
    const float* __restrict__ x2, const float* __restrict__ bias,
    float* __restrict__ dout) {
  int row = blockIdx.x, t = threadIdx.x;
  float4 xv = ((const float4*)(x2 + (size_t)row * D_))[t];
  float4 bv = ((const float4*)bias)[t];
  bf16x4 a = *(const bf16x4*)(p0 + (size_t)row * D_ + t * 4);
  bf16x4 b = *(const bf16x4*)(p1 + (size_t)row * D_ + t * 4);
  float4 o;
  o.x = xv.x + bv.x + (float)a[0] + (float)b[0];
  o.y = xv.y + bv.y + (float)a[1] + (float)b[1];
  o.z = xv.z + bv.z + (float)a[2] + (float)b[2];
  o.w = xv.w + bv.w + (float)a[3] + (float)b[3];
  ((float4*)(dout + (size_t)row * D_))[t] = o;
}

// ---------------- Weight transpose: fp32 [K,N] -> bf16 [N,K] ----------------
__global__ __launch_bounds__(256) void wtrans_kernel(const float* __restrict__ W,
    bf16* __restrict__ Wt, int K, int N) {
  __shared__ float tile[32][33];
  int n0 = blockIdx.x * 32, k0 = blockIdx.y * 32;
  int tx = threadIdx.x & 31, ty = threadIdx.x >> 5;
  #pragma unroll
  for (int i = 0; i < 4; i++)
    tile[ty + i*8][tx] = W[(size_t)(k0 + ty + i*8) * N + n0 + tx];
  __syncthreads();
  #pragma unroll
  for (int i = 0; i < 4; i++)
    Wt[(size_t)(n0 + ty + i*8) * K + k0 + tx] = (bf16)tile[tx][ty + i*8];
}

// ---------------- V transpose: bf16 [B*H][S,DH] -> [B*H][DH,S] ----------------
__global__ __launch_bounds__(256) void vtrans_kernel(const bf16* __restrict__ Vin,
    bf16* __restrict__ Vt) {
  __shared__ bf16 tile[32][34];
  size_t base = (size_t)blockIdx.z * (S_ * DH_);
  int s0 = blockIdx.x * 32, d0 = blockIdx.y * 32;
  int tx = threadIdx.x & 31, ty = threadIdx.x >> 5;
  #pragma unroll
  for (int i = 0; i < 4; i++)
    tile[ty + i*8][tx] = Vin[base + (size_t)(s0 + ty + i*8) * DH_ + d0 + tx];
  __syncthreads();
  #pragma unroll
  for (int i = 0; i < 4; i++)
    Vt[base + (size_t)(d0 + ty + i*8) * S_ + s0 + tx] = tile[tx][ty + i*8];
}

// fast GELU: x * sigmoid(2u), 2u*log2e = 2.3022585093*x*(1+0.044715 x^2)
// max dev from exact-erf gelu ~3e-4 -> negligible after w2 (sd 0.02)
__device__ __forceinline__ float gelu_fast(float x) {
  float e = __builtin_amdgcn_exp2f(2.3022585093f * x * (1.0f + 0.044715f * x * x));
  return x * e / (1.0f + e);
}

// ---------------- GEMM v2: single-barrier double-buffered, swizzled LDS ----------------
// C[M,N] = A[M,Ktot](bf16) @ Bt[N,Ktot]^T over k-slice [z*K, z*K+K)
// LDS slot (row, s) holds global k-granule (row, s ^ ((row>>1)&3)); readers XOR back.
// MODE 0: qkv scatter to [3][B,H,S,DH] bf16 (+bias)
// MODE 2: bf16 out = gelu(acc + bias)   (ffn1)
// MODE 5: bf16 partial store (split-K): z=0 -> outp, z=1 -> outp2, no bias
template<int MODE>
__global__ __launch_bounds__(256) void gemm_kernel(
    const bf16* __restrict__ A, const bf16* __restrict__ Bt,
    const float* __restrict__ bias, void* __restrict__ outp, void* __restrict__ outp2,
    int M, int N, int K, int lda) {
  __shared__ __align__(16) bf16 As[2][128 * 32];
  __shared__ __align__(16) bf16 Bs[2][128 * 32];
  int t = threadIdx.x;
  int wave = t >> 6, lane = t & 63;
  int lm = lane & 15, lg = lane >> 4;
  int m0 = blockIdx.y * 128, n0 = blockIdx.x * 128;
  size_t koff = (size_t)blockIdx.z * K;
  int wm = (wave >> 1) * 64, wn = (wave & 1) * 64;
  f32x4 acc[4][4] = {};

  // staging: thread t stages granule (srow, sslot) and (srow+64, sslot);
  // global column granule = sslot ^ ((srow>>1)&3)   [(srow+64)>>1 & 3 is identical]
  int srow = t >> 2, sslot = t & 3;
  int scol = (sslot ^ ((srow >> 1) & 3)) * 8;
  const bf16* Ag = A + (size_t)(m0 + srow) * lda + koff + scol;
  const bf16* Bg = Bt + (size_t)(n0 + srow) * lda + koff + scol;
  size_t half = (size_t)64 * lda;

  // fragment-read swizzle: row = wm/wn + i*16 + lm -> (row>>1)&3 == (lm>>1)&3
  int rsw = (lm >> 1) & 3;

  // prologue: stage k-tile 0 into buffer 0
  gll16(Ag, As[0] + t * 8);
  gll16(Ag + half, As[0] + 2048 + t * 8);
  gll16(Bg, Bs[0] + t * 8);
  gll16(Bg + half, Bs[0] + 2048 + t * 8);

  int buf = 0;
  for (int k0 = 0; k0 < K; k0 += 32, buf ^= 1) {
    __syncthreads();   // drains this tile's loads; prior readers of buf^1 done
    if (k0 + 32 < K) {
      gll16(Ag + k0 + 32, As[buf ^ 1] + t * 8);
      gll16(Ag + k0 + 32 + half, As[buf ^ 1] + 2048 + t * 8);
      gll16(Bg + k0 + 32, Bs[buf ^ 1] + t * 8);
      gll16(Bg + k0 + 32 + half, Bs[buf ^ 1] + 2048 + t * 8);
    }
    const bf16* Ab = As[buf];
    const bf16* Bb = Bs[buf];
    bf16x8 af[4], bfr[4];
    #pragma unroll
    for (int i = 0; i < 4; i++)
      af[i] = *(const bf16x8*)(Ab + (wm + i * 16 + lm) * 32 + (lg ^ rsw) * 8);
    #pragma unroll
    for (int j = 0; j < 4; j++)
      bfr[j] = *(const bf16x8*)(Bb + (wn + j * 16 + lm) * 32 + (lg ^ rsw) * 8);
    #pragma unroll
    for (int i = 0; i < 4; i++)
      #pragma unroll
      for (int j = 0; j < 4; j++)
        acc[i][j] = __builtin_amdgcn_mfma_f32_16x16x32_bf16(af[i], bfr[j], acc[i][j], 0, 0, 0);
  }

  bf16* pout = (MODE == 5) ? ((blockIdx.z == 0) ? (bf16*)outp : (bf16*)outp2) : (bf16*)outp;

  #pragma unroll
  for (int i = 0; i < 4; i++) {
    int row = m0 + wm + i * 16 + lg * 4;
    #pragma unroll
    for (int j = 0; j < 4; j++) {
      int col = n0 + wn + j * 16 + lm;
      float bcol = (MODE == 5) ? 0.f : bias[col];
      #pragma unroll
      for (int r = 0; r < 4; r++) {
        float v = acc[i][j][r] + bcol;
        int rr = row + r;
        if (MODE == 0) {
          int which = col >> 10, d = col & 1023;
          int hh = d >> 6, dh = d & 63;
          int bb = rr >> 11, s = rr & 2047;
          ((bf16*)outp)[(size_t)which * ((size_t)B_*H_*S_*DH_) +
              ((size_t)(bb * H_ + hh) * S_ + s) * DH_ + dh] = (bf16)v;
        } else if (MODE == 2) {
          ((bf16*)outp)[(size_t)rr * N + col] = (bf16)gelu_fast(v);
        } else {
          pout[(size_t)rr * N + col] = (bf16)v;
        }
      }
    }
  }
}

// ---------------- Flash attention v4 ----------------
// Fixed-max softmax, swizzled gll16 staging, ALiBi banding (skip far tiles),
// K/V double-buffer with ONE barrier per tile.
#define PSTR 68
__global__ __launch_bounds__(256, 3) void attn_kernel(
    const bf16* __restrict__ q, const bf16* __restrict__ k,
    const bf16* __restrict__ vT, bf16* __restrict__ ao) {
  __shared__ __align__(16) bf16 Ks[2][64 * 64];
  __shared__ __align__(16) bf16 Vs[2][64 * 64];
  __shared__ __align__(16) bf16 Ps[4 * 16 * PSTR];
  int t = threadIdx.x, wave = t >> 6, lane = t & 63;
  int lm = lane & 15, lg = lane >> 4;
  int q0 = blockIdx.x * 64;
  int h = blockIdx.y, b = blockIdx.z;
  size_t base = (size_t)(b * H_ + h) * ((size_t)S_ * DH_);
  const bf16* Q = q + base;
  const bf16* K = k + base;
  const bf16* V = vT + base;   // [DH][S]
  const float LOG2E = 1.4426950408889634f;
  float sl2 = exp2f(-0.5f * (float)(h + 1)) * LOG2E;
  float nslope = -sl2;
  const float qscale = 0.125f * LOG2E;
  const float FMAX = 8.0f;

  int W = (int)(24.0f / sl2);
  int jlo = (q0 - W) >> 6; if (jlo < 0) jlo = 0;
  int jhi = ((q0 + 63 + W) >> 6) + 1; if (jhi > S_ / 64) jhi = S_ / 64;

  bf16x8 qf[2];
  #pragma unroll
  for (int h2 = 0; h2 < 2; h2++) {
    bf16x8 v = *(const bf16x8*)(Q + (size_t)(q0 + wave * 16 + lm) * DH_ + h2 * 32 + lg * 8);
    #pragma unroll
    for (int e = 0; e < 8; e++) v[e] = (bf16)((float)v[e] * qscale);
    qf[h2] = v;
  }

  int row0 = t >> 3, jslot = t & 7;
  int gsw = (jslot ^ (row0 & 7)) << 3;
  const bf16* Ksrc0 = K + (size_t)row0 * DH_ + gsw;
  const bf16* Vsrc0 = V + (size_t)row0 * S_ + gsw;

  {
    int jt = jlo << 6;
    gll16(Ksrc0 + (size_t)jt * DH_, Ks[0] + (size_t)t * 8);
    gll16(Ksrc0 + (size_t)(jt + 32) * DH_, Ks[0] + (size_t)(t + 256) * 8);
    gll16(Vsrc0 + jt, Vs[0] + (size_t)t * 8);
    gll16(Vsrc0 + (size_t)32 * S_ + jt, Vs[0] + (size_t)(t + 256) * 8);
  }

  f32x4 oacc[4] = {};
  float rs[4] = {0.f, 0.f, 0.f, 0.f};
  int psw = lm & 7;

  for (int jj = jlo; jj < jhi; ++jj) {
    int buf = (jj - jlo) & 1;
    int jt = jj << 6;
    __syncthreads();
    if (jj + 1 < jhi) {
      int jn = (jj + 1) << 6;
      gll16(Ksrc0 + (size_t)jn * DH_, Ks[buf ^ 1] + (size_t)t * 8);
      gll16(Ksrc0 + (size_t)(jn + 32) * DH_, Ks[buf ^ 1] + (size_t)(t + 256) * 8);
      gll16(Vsrc0 + jn, Vs[buf ^ 1] + (size_t)t * 8);
      gll16(Vsrc0 + (size_t)32 * S_ + jn, Vs[buf ^ 1] + (size_t)(t + 256) * 8);
    }
    const bf16* Kb = Ks[buf];
    const bf16* Vb = Vs[buf];

    f32x4 sc[4];
    #pragma unroll
    for (int tt = 0; tt < 4; tt++) {
      f32x4 a = {-FMAX, -FMAX, -FMAX, -FMAX};
      int krow = tt * 16 + lm;
      bf16x8 kb0 = *(const bf16x8*)(Kb + (size_t)(krow * 8 + (lg ^ psw)) * 8);
      bf16x8 kb1 = *(const bf16x8*)(Kb + (size_t)(krow * 8 + ((lg + 4) ^ psw)) * 8);
      a = __builtin_amdgcn_mfma_f32_16x16x32_bf16(qf[0], kb0, a, 0, 0, 0);
      a = __builtin_amdgcn_mfma_f32_16x16x32_bf16(qf[1], kb1, a, 0, 0, 0);
      sc[tt] = a;
    }

    bf16* Pw = Ps + wave * (16 * PSTR);
    int i0 = q0 + wave * 16 + lg * 4;
    #pragma unroll
    for (int tt = 0; tt < 4; tt++) {
      float f0 = (float)(i0 - jt - tt * 16 - lm);
      #pragma unroll
      for (int r = 0; r < 4; r++) {
        float s2 = fmaf(nslope, fabsf(f0 + (float)r), sc[tt][r]);
        float p = __builtin_amdgcn_exp2f(s2);
        rs[r] += p;
        Pw[(lg * 4 + r) * PSTR + tt * 16 + lm] = (bf16)p;
      }
    }

    bf16x8 ap0 = *(const bf16x8*)(Pw + lm * PSTR + lg * 8);
    bf16x8 ap1 = *(const bf16x8*)(Pw + lm * PSTR + 32 + lg * 8);
    #pragma unroll
    for (int tt = 0; tt < 4; tt++) {
      int vrow = tt * 16 + lm;
      bf16x8 vb0 = *(const bf16x8*)(Vb + (size_t)(vrow * 8 + (lg ^ psw)) * 8);
      bf16x8 vb1 = *(const bf16x8*)(Vb + (size_t)(vrow * 8 + ((lg + 4) ^ psw)) * 8);
      oacc[tt] = __builtin_amdgcn_mfma_f32_16x16x32_bf16(ap0, vb0, oacc[tt], 0, 0, 0);
      oacc[tt] = __builtin_amdgcn_mfma_f32_16x16x32_bf16(ap1, vb1, oacc[tt], 0, 0, 0);
    }
  }

  #pragma unroll
  for (int r = 0; r < 4; r++) {
    #pragma unroll
    for (int off = 1; off < 16; off <<= 1)
      rs[r] += __shfl_xor(rs[r], off, 16);
  }

  #pragma unroll
  for (int r = 0; r < 4; r++) {
    float inv = 1.0f / rs[r];
    int row = q0 + wave * 16 + lg * 4 + r;
    #pragma unroll
    for (int tt = 0; tt < 4; tt++) {
      int col = h * 64 + tt * 16 + lm;
      ao[((size_t)(b * S_) + row) * D_ + col] = (bf16)(oacc[tt][r] * inv);
    }
  }
}

extern "C" void kernel_launch(void* const* d_in, const int* in_sizes, int n_in,
                              void* d_out, int out_size, void* d_ws, size_t ws_size,
                              hipStream_t stream) {
  const float* x      = (const float*)d_in[0];
  const float* scale1 = (const float*)d_in[1];
  const float* scale2 = (const float*)d_in[2];
  const float* w_qkv  = (const float*)d_in[3];
  const float* b_qkv  = (const float*)d_in[4];
  const float* w_out  = (const float*)d_in[5];
  const float* b_out  = (const float*)d_in[6];
  const float* w1     = (const float*)d_in[7];
  const float* b1     = (const float*)d_in[8];
  const float* w2     = (const float*)d_in[9];
  const float* b2     = (const float*)d_in[10];

  char* ws = (char*)d_ws;
  const size_t MB = 1024 * 1024;
  // layout (80 MB):
  bf16* xn    = (bf16*)(ws + 0);        // 0-8:   xn -> ao -> ffn2 partial 0
  bf16* qb    = (bf16*)(ws + 8*MB);     // 8-16:  q -> xn2
  bf16* kb    = (bf16*)(ws + 16*MB);    // 16-24: k -> out-proj partial 0 -> hbuf[0:8]
  bf16* vb    = (bf16*)(ws + 24*MB);    // 24-32: v -> out-proj partial 1 -> hbuf[8:16]
  bf16* vT    = (bf16*)(ws + 32*MB);    // 32-40: vT -> hbuf[16:24]
  bf16* wqkvT = (bf16*)(ws + 40*MB);    // 40-46: wqkvT -> hbuf[24:30]
  bf16* woutT = (bf16*)(ws + 46*MB);    // 46-48: woutT -> hbuf[30:32]
  bf16* w1T   = (bf16*)(ws + 48*MB);    // 48-56: w1T -> ffn2 partial 1
  bf16* w2T   = (bf16*)(ws + 56*MB);    // 56-64: w2T
  float* x2   = (float*)(ws + 64*MB);   // 64-80: x2 fp32
  bf16* xn2   = qb;
  bf16* pp0   = kb;                     // out-proj partials
  bf16* pp1   = vb;
  bf16* hbuf  = kb;                     // 16-48 [M,DFF]
  bf16* qp0   = xn;                     // ffn2 partials
  bf16* qp1   = w1T;
  bf16* ao    = xn;

  dim3 blk(256);
  wtrans_kernel<<<dim3(3072/32, 1024/32), blk, 0, stream>>>(w_qkv, wqkvT, 1024, 3072);
  wtrans_kernel<<<dim3(1024/32, 1024/32), blk, 0, stream>>>(w_out, woutT, 1024, 1024);
  wtrans_kernel<<<dim3(4096/32, 1024/32), blk, 0, stream>>>(w1, w1T, 1024, 4096);
  wtrans_kernel<<<dim3(1024/32, 4096/32), blk, 0, stream>>>(w2, w2T, 4096, 1024);

  rmsnorm_kernel<<<dim3(M_), blk, 0, stream>>>(x, scale1, xn);

  gemm_kernel<0><<<dim3(3072/128, M_/128, 1), blk, 0, stream>>>(
      xn, wqkvT, b_qkv, qb, nullptr, M_, 3072, 1024, 1024);

  vtrans_kernel<<<dim3(S_/32, DH_/32, B_*H_), blk, 0, stream>>>(vb, vT);

  attn_kernel<<<dim3(S_/64, H_, B_), blk, 0, stream>>>(qb, kb, vT, ao);

  // out-proj split-K=2: bf16 partials, then fused reduce+residual+bias+rmsnorm
  gemm_kernel<5><<<dim3(1024/128, M_/128, 2), blk, 0, stream>>>(
      ao, woutT, nullptr, pp0, pp1, M_, 1024, 512, 1024);
  reduce_rms_kernel<<<dim3(M_), blk, 0, stream>>>(pp0, pp1, x, b_out, scale2, x2, xn2);

  gemm_kernel<2><<<dim3(4096/128, M_/128, 1), blk, 0, stream>>>(
      xn2, w1T, b1, hbuf, nullptr, M_, 4096, 1024, 1024);

  // ffn2 split-K=2: bf16 partials, then fused reduce+residual+bias -> d_out
  gemm_kernel<5><<<dim3(1024/128, M_/128, 2), blk, 0, stream>>>(
      hbuf, w2T, nullptr, qp0, qp1, M_, 1024, 2048, 4096);
  reduce_out_kernel<<<dim3(M_), blk, 0, stream>>>(qp0, qp1, x2, b2, (float*)d_out);
}

// Round 7
// 373.584 us; speedup vs baseline: 1.4293x; 1.0111x over previous
//
#include <hip/hip_runtime.h>
#include <hip/hip_bf16.h>
#include <math.h>

#define B_ 2
#define S_ 2048
#define D_ 1024
#define H_ 16
#define DH_ 64
#define DFF_ 4096
#define M_ (B_*S_)

typedef __bf16 bf16;
typedef __bf16 bf16x8 __attribute__((ext_vector_type(8)));
typedef __bf16 bf16x4 __attribute__((ext_vector_type(4)));
typedef float f32x4 __attribute__((ext_vector_type(4)));

__device__ __forceinline__ void gll16(const void* g, void* l) {
  __builtin_amdgcn_global_load_lds(
      (const __attribute__((address_space(1))) void*)g,
      (__attribute__((address_space(3))) void*)l, 16, 0, 0);
}

// s_waitcnt immediates (gfx9 encoding): exp=7, lgkm=15 (don't wait), vmcnt=N
#define WAITCNT_VM4 0xF74
#define WAITCNT_VM0 0xF70

// ---------------- RMSNorm: fp32 [rows, D] -> bf16 ----------------
__global__ __launch_bounds__(256) void rmsnorm_kernel(const float* __restrict__ x,
    const float* __restrict__ scale, bf16* __restrict__ out) {
  __shared__ float red[4];
  int row = blockIdx.x, t = threadIdx.x;
  const float4* xr = (const float4*)(x + (size_t)row * D_);
  float4 v = xr[t];
  float ss = v.x*v.x + v.y*v.y + v.z*v.z + v.w*v.w;
  #pragma unroll
  for (int off = 32; off > 0; off >>= 1) ss += __shfl_down(ss, off, 64);
  if ((t & 63) == 0) red[t >> 6] = ss;
  __syncthreads();
  float tot = red[0] + red[1] + red[2] + red[3];
  float r = rsqrtf(tot * (1.0f / D_) + 1e-8f);
  float4 sc = ((const float4*)scale)[t];
  bf16x4 o;
  o[0] = (bf16)(v.x * sc.x * r);
  o[1] = (bf16)(v.y * sc.y * r);
  o[2] = (bf16)(v.z * sc.z * r);
  o[3] = (bf16)(v.w * sc.w * r);
  *(bf16x4*)(out + (size_t)row * D_ + t * 4) = o;
}

// ---------- reduce_rms: x2 = x + bias + p0 + p1 ; xn2 = rmsnorm(x2)*scale ----------
__global__ __launch_bounds__(256) void reduce_rms_kernel(
    const bf16* __restrict__ p0, const bf16* __restrict__ p1,
    const float* __restrict__ x, const float* __restrict__ bias,
    const float* __restrict__ scale, float* __restrict__ x2, bf16* __restrict__ xn2) {
  __shared__ float red[4];
  int row = blockIdx.x, t = threadIdx.x;
  float4 xv = ((const float4*)(x + (size_t)row * D_))[t];
  float4 bv = ((const float4*)bias)[t];
  bf16x4 a = *(const bf16x4*)(p0 + (size_t)row * D_ + t * 4);
  bf16x4 b = *(const bf16x4*)(p1 + (size_t)row * D_ + t * 4);
  float s0 = xv.x + bv.x + (float)a[0] + (float)b[0];
  float s1 = xv.y + bv.y + (float)a[1] + (float)b[1];
  float s2 = xv.z + bv.z + (float)a[2] + (float)b[2];
  float s3 = xv.w + bv.w + (float)a[3] + (float)b[3];
  float4 o; o.x = s0; o.y = s1; o.z = s2; o.w = s3;
  ((float4*)(x2 + (size_t)row * D_))[t] = o;
  float ss = s0*s0 + s1*s1 + s2*s2 + s3*s3;
  #pragma unroll
  for (int off = 32; off > 0; off >>= 1) ss += __shfl_down(ss, off, 64);
  if ((t & 63) == 0) red[t >> 6] = ss;
  __syncthreads();
  float tot = red[0] + red[1] + red[2] + red[3];
  float r = rsqrtf(tot * (1.0f / D_) + 1e-8f);
  float4 sc = ((const float4*)scale)[t];
  bf16x4 on;
  on[0] = (bf16)(s0 * sc.x * r);
  on[1] = (bf16)(s1 * sc.y * r);
  on[2] = (bf16)(s2 * sc.z * r);
  on[3] = (bf16)(s3 * sc.w * r);
  *(bf16x4*)(xn2 + (size_t)row * D_ + t * 4) = on;
}

// ---------- reduce_out: dout = x2 + bias + p0 + p1 ----------
__global__ __launch_bounds__(256) void reduce_out_kernel(
    const bf16* __restrict__ p0, const bf16* __restrict__ p1,
    const float* __restrict__ x2, const float* __restrict__ bias,
    float* __restrict__ dout) {
  int row = blockIdx.x, t = threadIdx.x;
  float4 xv = ((const float4*)(x2 + (size_t)row * D_))[t];
  float4 bv = ((const float4*)bias)[t];
  bf16x4 a = *(const bf16x4*)(p0 + (size_t)row * D_ + t * 4);
  bf16x4 b = *(const bf16x4*)(p1 + (size_t)row * D_ + t * 4);
  float4 o;
  o.x = xv.x + bv.x + (float)a[0] + (float)b[0];
  o.y = xv.y + bv.y + (float)a[1] + (float)b[1];
  o.z = xv.z + bv.z + (float)a[2] + (float)b[2];
  o.w = xv.w + bv.w + (float)a[3] + (float)b[3];
  ((float4*)(dout + (size_t)row * D_))[t] = o;
}

// ---------------- Weight transpose: fp32 [K,N] -> bf16 [N,K] ----------------
__global__ __launch_bounds__(256) void wtrans_kernel(const float* __restrict__ W,
    bf16* __restrict__ Wt, int K, int N) {
  __shared__ float tile[32][33];
  int n0 = blockIdx.x * 32, k0 = blockIdx.y * 32;
  int tx = threadIdx.x & 31, ty = threadIdx.x >> 5;
  #pragma unroll
  for (int i = 0; i < 4; i++)
    tile[ty + i*8][tx] = W[(size_t)(k0 + ty + i*8) * N + n0 + tx];
  __syncthreads();
  #pragma unroll
  for (int i = 0; i < 4; i++)
    Wt[(size_t)(n0 + ty + i*8) * K + k0 + tx] = (bf16)tile[tx][ty + i*8];
}

// ---------------- V transpose: bf16 [B*H][S,DH] -> [B*H][DH,S] ----------------
__global__ __launch_bounds__(256) void vtrans_kernel(const bf16* __restrict__ Vin,
    bf16* __restrict__ Vt) {
  __shared__ bf16 tile[32][34];
  size_t base = (size_t)blockIdx.z * (S_ * DH_);
  int s0 = blockIdx.x * 32, d0 = blockIdx.y * 32;
  int tx = threadIdx.x & 31, ty = threadIdx.x >> 5;
  #pragma unroll
  for (int i = 0; i < 4; i++)
    tile[ty + i*8][tx] = Vin[base + (size_t)(s0 + ty + i*8) * DH_ + d0 + tx];
  __syncthreads();
  #pragma unroll
  for (int i = 0; i < 4; i++)
    Vt[base + (size_t)(d0 + ty + i*8) * S_ + s0 + tx] = tile[tx][ty + i*8];
}

// fast GELU: x * sigmoid(2u), max dev from exact-erf gelu ~3e-4
__device__ __forceinline__ float gelu_fast(float x) {
  float e = __builtin_amdgcn_exp2f(2.3022585093f * x * (1.0f + 0.044715f * x * x));
  return x * e / (1.0f + e);
}

// ---------------- GEMM v3: 3-stage pipeline, raw barrier + vmcnt(4) ----------------
// C[M,N] = A[M,Ktot](bf16) @ Bt[N,Ktot]^T over k-slice [z*K, z*K+K)
// Steady state per iter j: waitcnt vmcnt(4) [drain tile j, keep tile j+1 in
// flight ACROSS the barrier], s_barrier, prefetch tile j+2 -> buf (j+2)%3,
// compute tile j. LDS slot (row,s) holds k-granule (row, s^((row>>1)&3)).
// MODE 0: qkv scatter to [3][B,H,S,DH] bf16 (+bias)
// MODE 2: bf16 out = gelu(acc + bias)   (ffn1)
// MODE 5: bf16 partial store (split-K): z=0 -> outp, z=1 -> outp2, no bias
template<int MODE>
__global__ __launch_bounds__(256) void gemm_kernel(
    const bf16* __restrict__ A, const bf16* __restrict__ Bt,
    const float* __restrict__ bias, void* __restrict__ outp, void* __restrict__ outp2,
    int M, int N, int K, int lda) {
  __shared__ __align__(16) bf16 As[3][128 * 32];
  __shared__ __align__(16) bf16 Bs[3][128 * 32];
  int t = threadIdx.x;
  int wave = t >> 6, lane = t & 63;
  int lm = lane & 15, lg = lane >> 4;
  int m0 = blockIdx.y * 128, n0 = blockIdx.x * 128;
  size_t koff = (size_t)blockIdx.z * K;
  int wm = (wave >> 1) * 64, wn = (wave & 1) * 64;
  f32x4 acc[4][4] = {};

  int srow = t >> 2, sslot = t & 3;
  int scol = (sslot ^ ((srow >> 1) & 3)) * 8;
  const bf16* Ag = A + (size_t)(m0 + srow) * lda + koff + scol;
  const bf16* Bg = Bt + (size_t)(n0 + srow) * lda + koff + scol;
  size_t half = (size_t)64 * lda;
  int rsw = (lm >> 1) & 3;
  int nk = K >> 5;

  // prologue: tiles 0 and 1
  gll16(Ag, As[0] + t * 8);
  gll16(Ag + half, As[0] + 2048 + t * 8);
  gll16(Bg, Bs[0] + t * 8);
  gll16(Bg + half, Bs[0] + 2048 + t * 8);
  if (nk > 1) {
    gll16(Ag + 32, As[1] + t * 8);
    gll16(Ag + 32 + half, As[1] + 2048 + t * 8);
    gll16(Bg + 32, Bs[1] + t * 8);
    gll16(Bg + 32 + half, Bs[1] + 2048 + t * 8);
  }

  int buf = 0;
  for (int j = 0; j < nk; ++j) {
    if (j + 1 < nk) __builtin_amdgcn_s_waitcnt(WAITCNT_VM4);
    else            __builtin_amdgcn_s_waitcnt(WAITCNT_VM0);
    __builtin_amdgcn_s_barrier();
    if (j + 2 < nk) {
      int k2 = (j + 2) << 5;
      int nbuf = buf + 2; if (nbuf >= 3) nbuf -= 3;
      bf16* Ad = As[nbuf];
      bf16* Bd = Bs[nbuf];
      gll16(Ag + k2, Ad + t * 8);
      gll16(Ag + k2 + half, Ad + 2048 + t * 8);
      gll16(Bg + k2, Bd + t * 8);
      gll16(Bg + k2 + half, Bd + 2048 + t * 8);
    }
    const bf16* Ab = As[buf];
    const bf16* Bb = Bs[buf];
    if (++buf == 3) buf = 0;
    bf16x8 af[4], bfr[4];
    #pragma unroll
    for (int i = 0; i < 4; i++)
      af[i] = *(const bf16x8*)(Ab + (wm + i * 16 + lm) * 32 + (lg ^ rsw) * 8);
    #pragma unroll
    for (int j2 = 0; j2 < 4; j2++)
      bfr[j2] = *(const bf16x8*)(Bb + (wn + j2 * 16 + lm) * 32 + (lg ^ rsw) * 8);
    #pragma unroll
    for (int i = 0; i < 4; i++)
      #pragma unroll
      for (int j2 = 0; j2 < 4; j2++)
        acc[i][j2] = __builtin_amdgcn_mfma_f32_16x16x32_bf16(af[i], bfr[j2], acc[i][j2], 0, 0, 0);
  }

  bf16* pout = (MODE == 5) ? ((blockIdx.z == 0) ? (bf16*)outp : (bf16*)outp2) : (bf16*)outp;

  #pragma unroll
  for (int i = 0; i < 4; i++) {
    int row = m0 + wm + i * 16 + lg * 4;
    #pragma unroll
    for (int j = 0; j < 4; j++) {
      int col = n0 + wn + j * 16 + lm;
      float bcol = (MODE == 5) ? 0.f : bias[col];
      #pragma unroll
      for (int r = 0; r < 4; r++) {
        float v = acc[i][j][r] + bcol;
        int rr = row + r;
        if (MODE == 0) {
          int which = col >> 10, d = col & 1023;
          int hh = d >> 6, dh = d & 63;
          int bb = rr >> 11, s = rr & 2047;
          ((bf16*)outp)[(size_t)which * ((size_t)B_*H_*S_*DH_) +
              ((size_t)(bb * H_ + hh) * S_ + s) * DH_ + dh] = (bf16)v;
        } else if (MODE == 2) {
          ((bf16*)outp)[(size_t)rr * N + col] = (bf16)gelu_fast(v);
        } else {
          pout[(size_t)rr * N + col] = (bf16)v;
        }
      }
    }
  }
}

// ---------------- Flash attention v4 (unchanged) ----------------
#define PSTR 68
__global__ __launch_bounds__(256, 3) void attn_kernel(
    const bf16* __restrict__ q, const bf16* __restrict__ k,
    const bf16* __restrict__ vT, bf16* __restrict__ ao) {
  __shared__ __align__(16) bf16 Ks[2][64 * 64];
  __shared__ __align__(16) bf16 Vs[2][64 * 64];
  __shared__ __align__(16) bf16 Ps[4 * 16 * PSTR];
  int t = threadIdx.x, wave = t >> 6, lane = t & 63;
  int lm = lane & 15, lg = lane >> 4;
  int q0 = blockIdx.x * 64;
  int h = blockIdx.y, b = blockIdx.z;
  size_t base = (size_t)(b * H_ + h) * ((size_t)S_ * DH_);
  const bf16* Q = q + base;
  const bf16* K = k + base;
  const bf16* V = vT + base;   // [DH][S]
  const float LOG2E = 1.4426950408889634f;
  float sl2 = exp2f(-0.5f * (float)(h + 1)) * LOG2E;
  float nslope = -sl2;
  const float qscale = 0.125f * LOG2E;
  const float FMAX = 8.0f;

  int W = (int)(24.0f / sl2);
  int jlo = (q0 - W) >> 6; if (jlo < 0) jlo = 0;
  int jhi = ((q0 + 63 + W) >> 6) + 1; if (jhi > S_ / 64) jhi = S_ / 64;

  bf16x8 qf[2];
  #pragma unroll
  for (int h2 = 0; h2 < 2; h2++) {
    bf16x8 v = *(const bf16x8*)(Q + (size_t)(q0 + wave * 16 + lm) * DH_ + h2 * 32 + lg * 8);
    #pragma unroll
    for (int e = 0; e < 8; e++) v[e] = (bf16)((float)v[e] * qscale);
    qf[h2] = v;
  }

  int row0 = t >> 3, jslot = t & 7;
  int gsw = (jslot ^ (row0 & 7)) << 3;
  const bf16* Ksrc0 = K + (size_t)row0 * DH_ + gsw;
  const bf16* Vsrc0 = V + (size_t)row0 * S_ + gsw;

  {
    int jt = jlo << 6;
    gll16(Ksrc0 + (size_t)jt * DH_, Ks[0] + (size_t)t * 8);
    gll16(Ksrc0 + (size_t)(jt + 32) * DH_, Ks[0] + (size_t)(t + 256) * 8);
    gll16(Vsrc0 + jt, Vs[0] + (size_t)t * 8);
    gll16(Vsrc0 + (size_t)32 * S_ + jt, Vs[0] + (size_t)(t + 256) * 8);
  }

  f32x4 oacc[4] = {};
  float rs[4] = {0.f, 0.f, 0.f, 0.f};
  int psw = lm & 7;

  for (int jj = jlo; jj < jhi; ++jj) {
    int buf = (jj - jlo) & 1;
    int jt = jj << 6;
    __syncthreads();
    if (jj + 1 < jhi) {
      int jn = (jj + 1) << 6;
      gll16(Ksrc0 + (size_t)jn * DH_, Ks[buf ^ 1] + (size_t)t * 8);
      gll16(Ksrc0 + (size_t)(jn + 32) * DH_, Ks[buf ^ 1] + (size_t)(t + 256) * 8);
      gll16(Vsrc0 + jn, Vs[buf ^ 1] + (size_t)t * 8);
      gll16(Vsrc0 + (size_t)32 * S_ + jn, Vs[buf ^ 1] + (size_t)(t + 256) * 8);
    }
    const bf16* Kb = Ks[buf];
    const bf16* Vb = Vs[buf];

    f32x4 sc[4];
    #pragma unroll
    for (int tt = 0; tt < 4; tt++) {
      f32x4 a = {-FMAX, -FMAX, -FMAX, -FMAX};
      int krow = tt * 16 + lm;
      bf16x8 kb0 = *(const bf16x8*)(Kb + (size_t)(krow * 8 + (lg ^ psw)) * 8);
      bf16x8 kb1 = *(const bf16x8*)(Kb + (size_t)(krow * 8 + ((lg + 4) ^ psw)) * 8);
      a = __builtin_amdgcn_mfma_f32_16x16x32_bf16(qf[0], kb0, a, 0, 0, 0);
      a = __builtin_amdgcn_mfma_f32_16x16x32_bf16(qf[1], kb1, a, 0, 0, 0);
      sc[tt] = a;
    }

    bf16* Pw = Ps + wave * (16 * PSTR);
    int i0 = q0 + wave * 16 + lg * 4;
    #pragma unroll
    for (int tt = 0; tt < 4; tt++) {
      float f0 = (float)(i0 - jt - tt * 16 - lm);
      #pragma unroll
      for (int r = 0; r < 4; r++) {
        float s2 = fmaf(nslope, fabsf(f0 + (float)r), sc[tt][r]);
        float p = __builtin_amdgcn_exp2f(s2);
        rs[r] += p;
        Pw[(lg * 4 + r) * PSTR + tt * 16 + lm] = (bf16)p;
      }
    }

    bf16x8 ap0 = *(const bf16x8*)(Pw + lm * PSTR + lg * 8);
    bf16x8 ap1 = *(const bf16x8*)(Pw + lm * PSTR + 32 + lg * 8);
    #pragma unroll
    for (int tt = 0; tt < 4; tt++) {
      int vrow = tt * 16 + lm;
      bf16x8 vb0 = *(const bf16x8*)(Vb + (size_t)(vrow * 8 + (lg ^ psw)) * 8);
      bf16x8 vb1 = *(const bf16x8*)(Vb + (size_t)(vrow * 8 + ((lg + 4) ^ psw)) * 8);
      oacc[tt] = __builtin_amdgcn_mfma_f32_16x16x32_bf16(ap0, vb0, oacc[tt], 0, 0, 0);
      oacc[tt] = __builtin_amdgcn_mfma_f32_16x16x32_bf16(ap1, vb1, oacc[tt], 0, 0, 0);
    }
  }

  #pragma unroll
  for (int r = 0; r < 4; r++) {
    #pragma unroll
    for (int off = 1; off < 16; off <<= 1)
      rs[r] += __shfl_xor(rs[r], off, 16);
  }

  #pragma unroll
  for (int r = 0; r < 4; r++) {
    float inv = 1.0f / rs[r];
    int row = q0 + wave * 16 + lg * 4 + r;
    #pragma unroll
    for (int tt = 0; tt < 4; tt++) {
      int col = h * 64 + tt * 16 + lm;
      ao[((size_t)(b * S_) + row) * D_ + col] = (bf16)(oacc[tt][r] * inv);
    }
  }
}

extern "C" void kernel_launch(void* const* d_in, const int* in_sizes, int n_in,
                              void* d_out, int out_size, void* d_ws, size_t ws_size,
                              hipStream_t stream) {
  const float* x      = (const float*)d_in[0];
  const float* scale1 = (const float*)d_in[1];
  const float* scale2 = (const float*)d_in[2];
  const float* w_qkv  = (const float*)d_in[3];
  const float* b_qkv  = (const float*)d_in[4];
  const float* w_out  = (const float*)d_in[5];
  const float* b_out  = (const float*)d_in[6];
  const float* w1     = (const float*)d_in[7];
  const float* b1     = (const float*)d_in[8];
  const float* w2     = (const float*)d_in[9];
  const float* b2     = (const float*)d_in[10];

  char* ws = (char*)d_ws;
  const size_t MB = 1024 * 1024;
  // layout (80 MB):
  bf16* xn    = (bf16*)(ws + 0);        // 0-8:   xn -> ao -> ffn2 partial 0
  bf16* qb    = (bf16*)(ws + 8*MB);     // 8-16:  q -> xn2
  bf16* kb    = (bf16*)(ws + 16*MB);    // 16-24: k -> out-proj partial 0 -> hbuf[0:8]
  bf16* vb    = (bf16*)(ws + 24*MB);    // 24-32: v -> out-proj partial 1 -> hbuf[8:16]
  bf16* vT    = (bf16*)(ws + 32*MB);    // 32-40: vT -> hbuf[16:24]
  bf16* wqkvT = (bf16*)(ws + 40*MB);    // 40-46: wqkvT -> hbuf[24:30]
  bf16* woutT = (bf16*)(ws + 46*MB);    // 46-48: woutT -> hbuf[30:32]
  bf16* w1T   = (bf16*)(ws + 48*MB);    // 48-56: w1T -> ffn2 partial 1
  bf16* w2T   = (bf16*)(ws + 56*MB);    // 56-64: w2T
  float* x2   = (float*)(ws + 64*MB);   // 64-80: x2 fp32
  bf16* xn2   = qb;
  bf16* pp0   = kb;                     // out-proj partials
  bf16* pp1   = vb;
  bf16* hbuf  = kb;                     // 16-48 [M,DFF]
  bf16* qp0   = xn;                     // ffn2 partials
  bf16* qp1   = w1T;
  bf16* ao    = xn;

  dim3 blk(256);
  wtrans_kernel<<<dim3(3072/32, 1024/32), blk, 0, stream>>>(w_qkv, wqkvT, 1024, 3072);
  wtrans_kernel<<<dim3(1024/32, 1024/32), blk, 0, stream>>>(w_out, woutT, 1024, 1024);
  wtrans_kernel<<<dim3(4096/32, 1024/32), blk, 0, stream>>>(w1, w1T, 1024, 4096);
  wtrans_kernel<<<dim3(1024/32, 4096/32), blk, 0, stream>>>(w2, w2T, 4096, 1024);

  rmsnorm_kernel<<<dim3(M_), blk, 0, stream>>>(x, scale1, xn);

  gemm_kernel<0><<<dim3(3072/128, M_/128, 1), blk, 0, stream>>>(
      xn, wqkvT, b_qkv, qb, nullptr, M_, 3072, 1024, 1024);

  vtrans_kernel<<<dim3(S_/32, DH_/32, B_*H_), blk, 0, stream>>>(vb, vT);

  attn_kernel<<<dim3(S_/64, H_, B_), blk, 0, stream>>>(qb, kb, vT, ao);

  // out-proj split-K=2: bf16 partials, then fused reduce+residual+bias+rmsnorm
  gemm_kernel<5><<<dim3(1024/128, M_/128, 2), blk, 0, stream>>>(
      ao, woutT, nullptr, pp0, pp1, M_, 1024, 512, 1024);
  reduce_rms_kernel<<<dim3(M_), blk, 0, stream>>>(pp0, pp1, x, b_out, scale2, x2, xn2);

  gemm_kernel<2><<<dim3(4096/128, M_/128, 1), blk, 0, stream>>>(
      xn2, w1T, b1, hbuf, nullptr, M_, 4096, 1024, 1024);

  // ffn2 split-K=2: bf16 partials, then fused reduce+residual+bias -> d_out
  gemm_kernel<5><<<dim3(1024/128, M_/128, 2), blk, 0, stream>>>(
      hbuf, w2T, nullptr, qp0, qp1, M_, 1024, 2048, 4096);
  reduce_out_kernel<<<dim3(M_), blk, 0, stream>>>(qp0, qp1, x2, b2, (float*)d_out);
}

// Round 8
// 371.169 us; speedup vs baseline: 1.4386x; 1.0065x over previous
//
#include <hip/hip_runtime.h>
#include <hip/hip_bf16.h>
#include <math.h>

#define B_ 2
#define S_ 2048
#define D_ 1024
#define H_ 16
#define DH_ 64
#define DFF_ 4096
#define M_ (B_*S_)

typedef __bf16 bf16;
typedef __bf16 bf16x8 __attribute__((ext_vector_type(8)));
typedef __bf16 bf16x4 __attribute__((ext_vector_type(4)));
typedef float f32x4 __attribute__((ext_vector_type(4)));

__device__ __forceinline__ void gll16(const void* g, void* l) {
  __builtin_amdgcn_global_load_lds(
      (const __attribute__((address_space(1))) void*)g,
      (__attribute__((address_space(3))) void*)l, 16, 0, 0);
}

// s_waitcnt immediates (gfx9 encoding): exp=7, lgkm=15 (don't wait), vmcnt=N
#define WAITCNT_VM4 0xF74
#define WAITCNT_VM0 0xF70

// ---------------- RMSNorm: fp32 [rows, D] -> bf16 ----------------
__global__ __launch_bounds__(256) void rmsnorm_kernel(const float* __restrict__ x,
    const float* __restrict__ scale, bf16* __restrict__ out) {
  __shared__ float red[4];
  int row = blockIdx.x, t = threadIdx.x;
  const float4* xr = (const float4*)(x + (size_t)row * D_);
  float4 v = xr[t];
  float ss = v.x*v.x + v.y*v.y + v.z*v.z + v.w*v.w;
  #pragma unroll
  for (int off = 32; off > 0; off >>= 1) ss += __shfl_down(ss, off, 64);
  if ((t & 63) == 0) red[t >> 6] = ss;
  __syncthreads();
  float tot = red[0] + red[1] + red[2] + red[3];
  float r = rsqrtf(tot * (1.0f / D_) + 1e-8f);
  float4 sc = ((const float4*)scale)[t];
  bf16x4 o;
  o[0] = (bf16)(v.x * sc.x * r);
  o[1] = (bf16)(v.y * sc.y * r);
  o[2] = (bf16)(v.z * sc.z * r);
  o[3] = (bf16)(v.w * sc.w * r);
  *(bf16x4*)(out + (size_t)row * D_ + t * 4) = o;
}

// ---------- reduce_rms: x2 = x + bias + p0 + p1 ; xn2 = rmsnorm(x2)*scale ----------
__global__ __launch_bounds__(256) void reduce_rms_kernel(
    const bf16* __restrict__ p0, const bf16* __restrict__ p1,
    const float* __restrict__ x, const float* __restrict__ bias,
    const float* __restrict__ scale, float* __restrict__ x2, bf16* __restrict__ xn2) {
  __shared__ float red[4];
  int row = blockIdx.x, t = threadIdx.x;
  float4 xv = ((const float4*)(x + (size_t)row * D_))[t];
  float4 bv = ((const float4*)bias)[t];
  bf16x4 a = *(const bf16x4*)(p0 + (size_t)row * D_ + t * 4);
  bf16x4 b = *(const bf16x4*)(p1 + (size_t)row * D_ + t * 4);
  float s0 = xv.x + bv.x + (float)a[0] + (float)b[0];
  float s1 = xv.y + bv.y + (float)a[1] + (float)b[1];
  float s2 = xv.z + bv.z + (float)a[2] + (float)b[2];
  float s3 = xv.w + bv.w + (float)a[3] + (float)b[3];
  float4 o; o.x = s0; o.y = s1; o.z = s2; o.w = s3;
  ((float4*)(x2 + (size_t)row * D_))[t] = o;
  float ss = s0*s0 + s1*s1 + s2*s2 + s3*s3;
  #pragma unroll
  for (int off = 32; off > 0; off >>= 1) ss += __shfl_down(ss, off, 64);
  if ((t & 63) == 0) red[t >> 6] = ss;
  __syncthreads();
  float tot = red[0] + red[1] + red[2] + red[3];
  float r = rsqrtf(tot * (1.0f / D_) + 1e-8f);
  float4 sc = ((const float4*)scale)[t];
  bf16x4 on;
  on[0] = (bf16)(s0 * sc.x * r);
  on[1] = (bf16)(s1 * sc.y * r);
  on[2] = (bf16)(s2 * sc.z * r);
  on[3] = (bf16)(s3 * sc.w * r);
  *(bf16x4*)(xn2 + (size_t)row * D_ + t * 4) = on;
}

// ---------- reduce_out: dout = x2 + bias + p0 + p1 ----------
__global__ __launch_bounds__(256) void reduce_out_kernel(
    const bf16* __restrict__ p0, const bf16* __restrict__ p1,
    const float* __restrict__ x2, const float* __restrict__ bias,
    float* __restrict__ dout) {
  int row = blockIdx.x, t = threadIdx.x;
  float4 xv = ((const float4*)(x2 + (size_t)row * D_))[t];
  float4 bv = ((const float4*)bias)[t];
  bf16x4 a = *(const bf16x4*)(p0 + (size_t)row * D_ + t * 4);
  bf16x4 b = *(const bf16x4*)(p1 + (size_t)row * D_ + t * 4);
  float4 o;
  o.x = xv.x + bv.x + (float)a[0] + (float)b[0];
  o.y = xv.y + bv.y + (float)a[1] + (float)b[1];
  o.z = xv.z + bv.z + (float)a[2] + (float)b[2];
  o.w = xv.w + bv.w + (float)a[3] + (float)b[3];
  ((float4*)(dout + (size_t)row * D_))[t] = o;
}

// ---------------- Weight transpose: fp32 [K,N] -> bf16 [N,K] ----------------
__global__ __launch_bounds__(256) void wtrans_kernel(const float* __restrict__ W,
    bf16* __restrict__ Wt, int K, int N) {
  __shared__ float tile[32][33];
  int n0 = blockIdx.x * 32, k0 = blockIdx.y * 32;
  int tx = threadIdx.x & 31, ty = threadIdx.x >> 5;
  #pragma unroll
  for (int i = 0; i < 4; i++)
    tile[ty + i*8][tx] = W[(size_t)(k0 + ty + i*8) * N + n0 + tx];
  __syncthreads();
  #pragma unroll
  for (int i = 0; i < 4; i++)
    Wt[(size_t)(n0 + ty + i*8) * K + k0 + tx] = (bf16)tile[tx][ty + i*8];
}

// ---------------- V transpose: bf16 [B*H][S,DH] -> [B*H][DH,S] ----------------
__global__ __launch_bounds__(256) void vtrans_kernel(const bf16* __restrict__ Vin,
    bf16* __restrict__ Vt) {
  __shared__ bf16 tile[32][34];
  size_t base = (size_t)blockIdx.z * (S_ * DH_);
  int s0 = blockIdx.x * 32, d0 = blockIdx.y * 32;
  int tx = threadIdx.x & 31, ty = threadIdx.x >> 5;
  #pragma unroll
  for (int i = 0; i < 4; i++)
    tile[ty + i*8][tx] = Vin[base + (size_t)(s0 + ty + i*8) * DH_ + d0 + tx];
  __syncthreads();
  #pragma unroll
  for (int i = 0; i < 4; i++)
    Vt[base + (size_t)(d0 + ty + i*8) * S_ + s0 + tx] = tile[tx][ty + i*8];
}

// fast GELU: x * sigmoid(2u), max dev from exact-erf gelu ~3e-4
__device__ __forceinline__ float gelu_fast(float x) {
  float e = __builtin_amdgcn_exp2f(2.3022585093f * x * (1.0f + 0.044715f * x * x));
  return x * e / (1.0f + e);
}

// ---------------- GEMM v3: 3-stage pipeline, raw barrier + vmcnt(4) ----------------
template<int MODE>
__global__ __launch_bounds__(256) void gemm_kernel(
    const bf16* __restrict__ A, const bf16* __restrict__ Bt,
    const float* __restrict__ bias, void* __restrict__ outp, void* __restrict__ outp2,
    int M, int N, int K, int lda) {
  __shared__ __align__(16) bf16 As[3][128 * 32];
  __shared__ __align__(16) bf16 Bs[3][128 * 32];
  int t = threadIdx.x;
  int wave = t >> 6, lane = t & 63;
  int lm = lane & 15, lg = lane >> 4;
  int m0 = blockIdx.y * 128, n0 = blockIdx.x * 128;
  size_t koff = (size_t)blockIdx.z * K;
  int wm = (wave >> 1) * 64, wn = (wave & 1) * 64;
  f32x4 acc[4][4] = {};

  int srow = t >> 2, sslot = t & 3;
  int scol = (sslot ^ ((srow >> 1) & 3)) * 8;
  const bf16* Ag = A + (size_t)(m0 + srow) * lda + koff + scol;
  const bf16* Bg = Bt + (size_t)(n0 + srow) * lda + koff + scol;
  size_t half = (size_t)64 * lda;
  int rsw = (lm >> 1) & 3;
  int nk = K >> 5;

  gll16(Ag, As[0] + t * 8);
  gll16(Ag + half, As[0] + 2048 + t * 8);
  gll16(Bg, Bs[0] + t * 8);
  gll16(Bg + half, Bs[0] + 2048 + t * 8);
  if (nk > 1) {
    gll16(Ag + 32, As[1] + t * 8);
    gll16(Ag + 32 + half, As[1] + 2048 + t * 8);
    gll16(Bg + 32, Bs[1] + t * 8);
    gll16(Bg + 32 + half, Bs[1] + 2048 + t * 8);
  }

  int buf = 0;
  for (int j = 0; j < nk; ++j) {
    if (j + 1 < nk) __builtin_amdgcn_s_waitcnt(WAITCNT_VM4);
    else            __builtin_amdgcn_s_waitcnt(WAITCNT_VM0);
    __builtin_amdgcn_s_barrier();
    if (j + 2 < nk) {
      int k2 = (j + 2) << 5;
      int nbuf = buf + 2; if (nbuf >= 3) nbuf -= 3;
      bf16* Ad = As[nbuf];
      bf16* Bd = Bs[nbuf];
      gll16(Ag + k2, Ad + t * 8);
      gll16(Ag + k2 + half, Ad + 2048 + t * 8);
      gll16(Bg + k2, Bd + t * 8);
      gll16(Bg + k2 + half, Bd + 2048 + t * 8);
    }
    const bf16* Ab = As[buf];
    const bf16* Bb = Bs[buf];
    if (++buf == 3) buf = 0;
    bf16x8 af[4], bfr[4];
    #pragma unroll
    for (int i = 0; i < 4; i++)
      af[i] = *(const bf16x8*)(Ab + (wm + i * 16 + lm) * 32 + (lg ^ rsw) * 8);
    #pragma unroll
    for (int j2 = 0; j2 < 4; j2++)
      bfr[j2] = *(const bf16x8*)(Bb + (wn + j2 * 16 + lm) * 32 + (lg ^ rsw) * 8);
    #pragma unroll
    for (int i = 0; i < 4; i++)
      #pragma unroll
      for (int j2 = 0; j2 < 4; j2++)
        acc[i][j2] = __builtin_amdgcn_mfma_f32_16x16x32_bf16(af[i], bfr[j2], acc[i][j2], 0, 0, 0);
  }

  bf16* pout = (MODE == 5) ? ((blockIdx.z == 0) ? (bf16*)outp : (bf16*)outp2) : (bf16*)outp;

  #pragma unroll
  for (int i = 0; i < 4; i++) {
    int row = m0 + wm + i * 16 + lg * 4;
    #pragma unroll
    for (int j = 0; j < 4; j++) {
      int col = n0 + wn + j * 16 + lm;
      float bcol = (MODE == 5) ? 0.f : bias[col];
      #pragma unroll
      for (int r = 0; r < 4; r++) {
        float v = acc[i][j][r] + bcol;
        int rr = row + r;
        if (MODE == 0) {
          int which = col >> 10, d = col & 1023;
          int hh = d >> 6, dh = d & 63;
          int bb = rr >> 11, s = rr & 2047;
          ((bf16*)outp)[(size_t)which * ((size_t)B_*H_*S_*DH_) +
              ((size_t)(bb * H_ + hh) * S_ + s) * DH_ + dh] = (bf16)v;
        } else if (MODE == 2) {
          ((bf16*)outp)[(size_t)rr * N + col] = (bf16)gelu_fast(v);
        } else {
          pout[(size_t)rr * N + col] = (bf16)v;
        }
      }
    }
  }
}

// ---------------- Flash attention v5: 2-way balanced KV-chunk split ----------------
// Fixed-max softmax => chunks combine ADDITIVELY: o = (p0+p1)/(rs0+rs1).
// grid (32 qtiles, 16 heads DESCENDING work, B*2 chunk): heavy blocks first.
// Each block writes un-normalized bf16 o-partial [64x64] + fp32 row-sums.
#define PSTR 68
__global__ __launch_bounds__(256, 3) void attn_kernel(
    const bf16* __restrict__ q, const bf16* __restrict__ k,
    const bf16* __restrict__ vT, bf16* __restrict__ pbuf, float* __restrict__ rsbuf) {
  __shared__ __align__(16) bf16 Ks[2][64 * 64];
  __shared__ __align__(16) bf16 Vs[2][64 * 64];
  __shared__ __align__(16) bf16 Ps[4 * 16 * PSTR];
  int t = threadIdx.x, wave = t >> 6, lane = t & 63;
  int lm = lane & 15, lg = lane >> 4;
  int qt = blockIdx.x, q0 = qt * 64;
  int h = 15 - blockIdx.y;               // heavy (small-slope) heads dispatch first
  int b = blockIdx.z >> 1, c = blockIdx.z & 1;
  size_t base = (size_t)(b * H_ + h) * ((size_t)S_ * DH_);
  const bf16* Q = q + base;
  const bf16* K = k + base;
  const bf16* V = vT + base;   // [DH][S]
  const float LOG2E = 1.4426950408889634f;
  float sl2 = exp2f(-0.5f * (float)(h + 1)) * LOG2E;
  float nslope = -sl2;
  const float qscale = 0.125f * LOG2E;
  const float FMAX = 8.0f;

  int W = (int)(24.0f / sl2);
  int jlo = (q0 - W) >> 6; if (jlo < 0) jlo = 0;
  int jhi = ((q0 + 63 + W) >> 6) + 1; if (jhi > S_ / 64) jhi = S_ / 64;
  int n = jhi - jlo, nc0 = (n + 1) >> 1;
  int cjlo = c ? jlo + nc0 : jlo;
  int cjhi = c ? jhi : jlo + nc0;
  int slot = ((b * H_ + h) * 32 + qt) * 2 + c;
  bf16* Pout = pbuf + (size_t)slot * 4096;
  float* Rout = rsbuf + (size_t)slot * 64;

  if (cjlo >= cjhi) {   // empty chunk: zero-fill partial (ws is poisoned)
    uint4 z = {0, 0, 0, 0};
    *(uint4*)(Pout + t * 8) = z;
    *(uint4*)(Pout + 2048 + t * 8) = z;
    if (t < 64) Rout[t] = 0.f;
    return;
  }

  bf16x8 qf[2];
  #pragma unroll
  for (int h2 = 0; h2 < 2; h2++) {
    bf16x8 v = *(const bf16x8*)(Q + (size_t)(q0 + wave * 16 + lm) * DH_ + h2 * 32 + lg * 8);
    #pragma unroll
    for (int e = 0; e < 8; e++) v[e] = (bf16)((float)v[e] * qscale);
    qf[h2] = v;
  }

  int row0 = t >> 3, jslot = t & 7;
  int gsw = (jslot ^ (row0 & 7)) << 3;
  const bf16* Ksrc0 = K + (size_t)row0 * DH_ + gsw;
  const bf16* Vsrc0 = V + (size_t)row0 * S_ + gsw;

  {
    int jt = cjlo << 6;
    gll16(Ksrc0 + (size_t)jt * DH_, Ks[0] + (size_t)t * 8);
    gll16(Ksrc0 + (size_t)(jt + 32) * DH_, Ks[0] + (size_t)(t + 256) * 8);
    gll16(Vsrc0 + jt, Vs[0] + (size_t)t * 8);
    gll16(Vsrc0 + (size_t)32 * S_ + jt, Vs[0] + (size_t)(t + 256) * 8);
  }

  f32x4 oacc[4] = {};
  float rs[4] = {0.f, 0.f, 0.f, 0.f};
  int psw = lm & 7;

  for (int jj = cjlo; jj < cjhi; ++jj) {
    int buf = (jj - cjlo) & 1;
    int jt = jj << 6;
    __syncthreads();
    if (jj + 1 < cjhi) {
      int jn = (jj + 1) << 6;
      gll16(Ksrc0 + (size_t)jn * DH_, Ks[buf ^ 1] + (size_t)t * 8);
      gll16(Ksrc0 + (size_t)(jn + 32) * DH_, Ks[buf ^ 1] + (size_t)(t + 256) * 8);
      gll16(Vsrc0 + jn, Vs[buf ^ 1] + (size_t)t * 8);
      gll16(Vsrc0 + (size_t)32 * S_ + jn, Vs[buf ^ 1] + (size_t)(t + 256) * 8);
    }
    const bf16* Kb = Ks[buf];
    const bf16* Vb = Vs[buf];

    f32x4 sc[4];
    #pragma unroll
    for (int tt = 0; tt < 4; tt++) {
      f32x4 a = {-FMAX, -FMAX, -FMAX, -FMAX};
      int krow = tt * 16 + lm;
      bf16x8 kb0 = *(const bf16x8*)(Kb + (size_t)(krow * 8 + (lg ^ psw)) * 8);
      bf16x8 kb1 = *(const bf16x8*)(Kb + (size_t)(krow * 8 + ((lg + 4) ^ psw)) * 8);
      a = __builtin_amdgcn_mfma_f32_16x16x32_bf16(qf[0], kb0, a, 0, 0, 0);
      a = __builtin_amdgcn_mfma_f32_16x16x32_bf16(qf[1], kb1, a, 0, 0, 0);
      sc[tt] = a;
    }

    bf16* Pw = Ps + wave * (16 * PSTR);
    int i0 = q0 + wave * 16 + lg * 4;
    #pragma unroll
    for (int tt = 0; tt < 4; tt++) {
      float f0 = (float)(i0 - jt - tt * 16 - lm);
      #pragma unroll
      for (int r = 0; r < 4; r++) {
        float s2 = fmaf(nslope, fabsf(f0 + (float)r), sc[tt][r]);
        float p = __builtin_amdgcn_exp2f(s2);
        rs[r] += p;
        Pw[(lg * 4 + r) * PSTR + tt * 16 + lm] = (bf16)p;
      }
    }

    bf16x8 ap0 = *(const bf16x8*)(Pw + lm * PSTR + lg * 8);
    bf16x8 ap1 = *(const bf16x8*)(Pw + lm * PSTR + 32 + lg * 8);
    #pragma unroll
    for (int tt = 0; tt < 4; tt++) {
      int vrow = tt * 16 + lm;
      bf16x8 vb0 = *(const bf16x8*)(Vb + (size_t)(vrow * 8 + (lg ^ psw)) * 8);
      bf16x8 vb1 = *(const bf16x8*)(Vb + (size_t)(vrow * 8 + ((lg + 4) ^ psw)) * 8);
      oacc[tt] = __builtin_amdgcn_mfma_f32_16x16x32_bf16(ap0, vb0, oacc[tt], 0, 0, 0);
      oacc[tt] = __builtin_amdgcn_mfma_f32_16x16x32_bf16(ap1, vb1, oacc[tt], 0, 0, 0);
    }
  }

  #pragma unroll
  for (int r = 0; r < 4; r++) {
    #pragma unroll
    for (int off = 1; off < 16; off <<= 1)
      rs[r] += __shfl_xor(rs[r], off, 16);
  }

  #pragma unroll
  for (int r = 0; r < 4; r++) {
    int lrow = wave * 16 + lg * 4 + r;
    if (lm == 0) Rout[lrow] = rs[r];
    #pragma unroll
    for (int tt = 0; tt < 4; tt++)
      Pout[lrow * 64 + tt * 16 + lm] = (bf16)oacc[tt][r];
  }
}

// ---------------- attn combine: ao = (p0+p1)/(rs0+rs1) ----------------
__global__ __launch_bounds__(256) void attn_combine_kernel(
    const bf16* __restrict__ pbuf, const float* __restrict__ rsbuf,
    bf16* __restrict__ ao) {
  int qt = blockIdx.x, h = blockIdx.y, b = blockIdx.z;
  int slot0 = ((b * H_ + h) * 32 + qt) * 2;
  int t = threadIdx.x;
  int row = t >> 2, cg = (t & 3) * 16;
  const bf16* P0 = pbuf + (size_t)slot0 * 4096 + row * 64 + cg;
  const bf16* P1 = pbuf + (size_t)(slot0 + 1) * 4096 + row * 64 + cg;
  float inv = 1.0f / (rsbuf[(size_t)slot0 * 64 + row] + rsbuf[(size_t)(slot0 + 1) * 64 + row]);
  bf16x8 a0 = *(const bf16x8*)P0, a1 = *(const bf16x8*)(P0 + 8);
  bf16x8 b0 = *(const bf16x8*)P1, b1 = *(const bf16x8*)(P1 + 8);
  bf16x8 o0, o1;
  #pragma unroll
  for (int e = 0; e < 8; e++) {
    o0[e] = (bf16)(((float)a0[e] + (float)b0[e]) * inv);
    o1[e] = (bf16)(((float)a1[e] + (float)b1[e]) * inv);
  }
  bf16* dst = ao + ((size_t)(b * S_) + qt * 64 + row) * D_ + h * 64 + cg;
  *(bf16x8*)dst = o0;
  *(bf16x8*)(dst + 8) = o1;
}

extern "C" void kernel_launch(void* const* d_in, const int* in_sizes, int n_in,
                              void* d_out, int out_size, void* d_ws, size_t ws_size,
                              hipStream_t stream) {
  const float* x      = (const float*)d_in[0];
  const float* scale1 = (const float*)d_in[1];
  const float* scale2 = (const float*)d_in[2];
  const float* w_qkv  = (const float*)d_in[3];
  const float* b_qkv  = (const float*)d_in[4];
  const float* w_out  = (const float*)d_in[5];
  const float* b_out  = (const float*)d_in[6];
  const float* w1     = (const float*)d_in[7];
  const float* b1     = (const float*)d_in[8];
  const float* w2     = (const float*)d_in[9];
  const float* b2     = (const float*)d_in[10];

  char* ws = (char*)d_ws;
  const size_t MB = 1024 * 1024;
  // layout (80 MB):
  bf16* xn    = (bf16*)(ws + 0);        // 0-8:   xn -> ao -> ffn2 partial 0
  bf16* qb    = (bf16*)(ws + 8*MB);     // 8-16:  q -> xn2
  bf16* kb    = (bf16*)(ws + 16*MB);    // 16-24: k -> out-proj partial 0 -> hbuf[0:8]
  bf16* vb    = (bf16*)(ws + 24*MB);    // 24-32: v -> out-proj partial 1 -> hbuf[8:16]
  bf16* vT    = (bf16*)(ws + 32*MB);    // 32-40: vT -> hbuf[16:24]
  bf16* wqkvT = (bf16*)(ws + 40*MB);    // 40-46: wqkvT; dead after qkv -> attn rsbuf
  bf16* woutT = (bf16*)(ws + 46*MB);    // 46-48: woutT -> hbuf[30:32]
  bf16* w1T   = (bf16*)(ws + 48*MB);    // 48-56: w1T -> ffn2 partial 1
  bf16* w2T   = (bf16*)(ws + 56*MB);    // 56-64: w2T
  float* x2   = (float*)(ws + 64*MB);   // 64-80: attn o-partials (16MB), then x2 fp32
  bf16* xn2   = qb;
  bf16* pp0   = kb;                     // out-proj partials
  bf16* pp1   = vb;
  bf16* hbuf  = kb;                     // 16-48 [M,DFF]
  bf16* qp0   = xn;                     // ffn2 partials
  bf16* qp1   = w1T;
  bf16* ao    = xn;
  bf16* pbuf  = (bf16*)(ws + 64*MB);    // attn o-partials (dead once combine runs)
  float* rsbuf = (float*)(ws + 40*MB);  // attn row-sums (0.5MB; wqkvT dead by then)

  dim3 blk(256);
  wtrans_kernel<<<dim3(3072/32, 1024/32), blk, 0, stream>>>(w_qkv, wqkvT, 1024, 3072);
  wtrans_kernel<<<dim3(1024/32, 1024/32), blk, 0, stream>>>(w_out, woutT, 1024, 1024);
  wtrans_kernel<<<dim3(4096/32, 1024/32), blk, 0, stream>>>(w1, w1T, 1024, 4096);
  wtrans_kernel<<<dim3(1024/32, 4096/32), blk, 0, stream>>>(w2, w2T, 4096, 1024);

  rmsnorm_kernel<<<dim3(M_), blk, 0, stream>>>(x, scale1, xn);

  gemm_kernel<0><<<dim3(3072/128, M_/128, 1), blk, 0, stream>>>(
      xn, wqkvT, b_qkv, qb, nullptr, M_, 3072, 1024, 1024);

  vtrans_kernel<<<dim3(S_/32, DH_/32, B_*H_), blk, 0, stream>>>(vb, vT);

  attn_kernel<<<dim3(S_/64, H_, B_*2), blk, 0, stream>>>(qb, kb, vT, pbuf, rsbuf);
  attn_combine_kernel<<<dim3(S_/64, H_, B_), blk, 0, stream>>>(pbuf, rsbuf, ao);

  // out-proj split-K=2: bf16 partials, then fused reduce+residual+bias+rmsnorm
  gemm_kernel<5><<<dim3(1024/128, M_/128, 2), blk, 0, stream>>>(
      ao, woutT, nullptr, pp0, pp1, M_, 1024, 512, 1024);
  reduce_rms_kernel<<<dim3(M_), blk, 0, stream>>>(pp0, pp1, x, b_out, scale2, x2, xn2);

  gemm_kernel<2><<<dim3(4096/128, M_/128, 1), blk, 0, stream>>>(
      xn2, w1T, b1, hbuf, nullptr, M_, 4096, 1024, 1024);

  // ffn2 split-K=2: bf16 partials, then fused reduce+residual+bias -> d_out
  gemm_kernel<5><<<dim3(1024/128, M_/128, 2), blk, 0, stream>>>(
      hbuf, w2T, nullptr, qp0, qp1, M_, 1024, 2048, 4096);
  reduce_out_kernel<<<dim3(M_), blk, 0, stream>>>(qp0, qp1, x2, b2, (float*)d_out);
}

// Round 9
// 361.279 us; speedup vs baseline: 1.4780x; 1.0274x over previous
//
#include <hip/hip_runtime.h>
#include <hip/hip_bf16.h>
#include <math.h>

#define B_ 2
#define S_ 2048
#define D_ 1024
#define H_ 16
#define DH_ 64
#define DFF_ 4096
#define M_ (B_*S_)

typedef __bf16 bf16;
typedef __bf16 bf16x8 __attribute__((ext_vector_type(8)));
typedef __bf16 bf16x4 __attribute__((ext_vector_type(4)));
typedef float f32x4 __attribute__((ext_vector_type(4)));

__device__ __forceinline__ void gll16(const void* g, void* l) {
  __builtin_amdgcn_global_load_lds(
      (const __attribute__((address_space(1))) void*)g,
      (__attribute__((address_space(3))) void*)l, 16, 0, 0);
}

// s_waitcnt immediates (gfx9 encoding): exp=7, lgkm=15 (don't wait), vmcnt=N
#define WAITCNT_VM4 0xF74
#define WAITCNT_VM0 0xF70

// ---------------- RMSNorm: fp32 [rows, D] -> bf16 ----------------
__global__ __launch_bounds__(256) void rmsnorm_kernel(const float* __restrict__ x,
    const float* __restrict__ scale, bf16* __restrict__ out) {
  __shared__ float red[4];
  int row = blockIdx.x, t = threadIdx.x;
  const float4* xr = (const float4*)(x + (size_t)row * D_);
  float4 v = xr[t];
  float ss = v.x*v.x + v.y*v.y + v.z*v.z + v.w*v.w;
  #pragma unroll
  for (int off = 32; off > 0; off >>= 1) ss += __shfl_down(ss, off, 64);
  if ((t & 63) == 0) red[t >> 6] = ss;
  __syncthreads();
  float tot = red[0] + red[1] + red[2] + red[3];
  float r = rsqrtf(tot * (1.0f / D_) + 1e-8f);
  float4 sc = ((const float4*)scale)[t];
  bf16x4 o;
  o[0] = (bf16)(v.x * sc.x * r);
  o[1] = (bf16)(v.y * sc.y * r);
  o[2] = (bf16)(v.z * sc.z * r);
  o[3] = (bf16)(v.w * sc.w * r);
  *(bf16x4*)(out + (size_t)row * D_ + t * 4) = o;
}

// ---------- reduce_rms: x2 = x + bias + p0 + p1 ; xn2 = rmsnorm(x2)*scale ----------
__global__ __launch_bounds__(256) void reduce_rms_kernel(
    const bf16* __restrict__ p0, const bf16* __restrict__ p1,
    const float* __restrict__ x, const float* __restrict__ bias,
    const float* __restrict__ scale, float* __restrict__ x2, bf16* __restrict__ xn2) {
  __shared__ float red[4];
  int row = blockIdx.x, t = threadIdx.x;
  float4 xv = ((const float4*)(x + (size_t)row * D_))[t];
  float4 bv = ((const float4*)bias)[t];
  bf16x4 a = *(const bf16x4*)(p0 + (size_t)row * D_ + t * 4);
  bf16x4 b = *(const bf16x4*)(p1 + (size_t)row * D_ + t * 4);
  float s0 = xv.x + bv.x + (float)a[0] + (float)b[0];
  float s1 = xv.y + bv.y + (float)a[1] + (float)b[1];
  float s2 = xv.z + bv.z + (float)a[2] + (float)b[2];
  float s3 = xv.w + bv.w + (float)a[3] + (float)b[3];
  float4 o; o.x = s0; o.y = s1; o.z = s2; o.w = s3;
  ((float4*)(x2 + (size_t)row * D_))[t] = o;
  float ss = s0*s0 + s1*s1 + s2*s2 + s3*s3;
  #pragma unroll
  for (int off = 32; off > 0; off >>= 1) ss += __shfl_down(ss, off, 64);
  if ((t & 63) == 0) red[t >> 6] = ss;
  __syncthreads();
  float tot = red[0] + red[1] + red[2] + red[3];
  float r = rsqrtf(tot * (1.0f / D_) + 1e-8f);
  float4 sc = ((const float4*)scale)[t];
  bf16x4 on;
  on[0] = (bf16)(s0 * sc.x * r);
  on[1] = (bf16)(s1 * sc.y * r);
  on[2] = (bf16)(s2 * sc.z * r);
  on[3] = (bf16)(s3 * sc.w * r);
  *(bf16x4*)(xn2 + (size_t)row * D_ + t * 4) = on;
}

// ---------- reduce_out: dout = x2 + bias + p0 + p1 ----------
__global__ __launch_bounds__(256) void reduce_out_kernel(
    const bf16* __restrict__ p0, const bf16* __restrict__ p1,
    const float* __restrict__ x2, const float* __restrict__ bias,
    float* __restrict__ dout) {
  int row = blockIdx.x, t = threadIdx.x;
  float4 xv = ((const float4*)(x2 + (size_t)row * D_))[t];
  float4 bv = ((const float4*)bias)[t];
  bf16x4 a = *(const bf16x4*)(p0 + (size_t)row * D_ + t * 4);
  bf16x4 b = *(const bf16x4*)(p1 + (size_t)row * D_ + t * 4);
  float4 o;
  o.x = xv.x + bv.x + (float)a[0] + (float)b[0];
  o.y = xv.y + bv.y + (float)a[1] + (float)b[1];
  o.z = xv.z + bv.z + (float)a[2] + (float)b[2];
  o.w = xv.w + bv.w + (float)a[3] + (float)b[3];
  ((float4*)(dout + (size_t)row * D_))[t] = o;
}

// ---------------- Weight transpose: fp32 [K,N] -> bf16 [N,K] ----------------
__global__ __launch_bounds__(256) void wtrans_kernel(const float* __restrict__ W,
    bf16* __restrict__ Wt, int K, int N) {
  __shared__ float tile[32][33];
  int n0 = blockIdx.x * 32, k0 = blockIdx.y * 32;
  int tx = threadIdx.x & 31, ty = threadIdx.x >> 5;
  #pragma unroll
  for (int i = 0; i < 4; i++)
    tile[ty + i*8][tx] = W[(size_t)(k0 + ty + i*8) * N + n0 + tx];
  __syncthreads();
  #pragma unroll
  for (int i = 0; i < 4; i++)
    Wt[(size_t)(n0 + ty + i*8) * K + k0 + tx] = (bf16)tile[tx][ty + i*8];
}

// ---------------- V transpose: bf16 [B*H][S,DH] -> [B*H][DH,S] ----------------
__global__ __launch_bounds__(256) void vtrans_kernel(const bf16* __restrict__ Vin,
    bf16* __restrict__ Vt) {
  __shared__ bf16 tile[32][34];
  size_t base = (size_t)blockIdx.z * (S_ * DH_);
  int s0 = blockIdx.x * 32, d0 = blockIdx.y * 32;
  int tx = threadIdx.x & 31, ty = threadIdx.x >> 5;
  #pragma unroll
  for (int i = 0; i < 4; i++)
    tile[ty + i*8][tx] = Vin[base + (size_t)(s0 + ty + i*8) * DH_ + d0 + tx];
  __syncthreads();
  #pragma unroll
  for (int i = 0; i < 4; i++)
    Vt[base + (size_t)(d0 + ty + i*8) * S_ + s0 + tx] = tile[tx][ty + i*8];
}

// fast GELU: x * sigmoid(2u), max dev from exact-erf gelu ~3e-4
__device__ __forceinline__ float gelu_fast(float x) {
  float e = __builtin_amdgcn_exp2f(2.3022585093f * x * (1.0f + 0.044715f * x * x));
  return x * e / (1.0f + e);
}

// ---------------- GEMM v3: 3-stage pipeline, raw barrier + vmcnt(4) ----------------
template<int MODE>
__global__ __launch_bounds__(256) void gemm_kernel(
    const bf16* __restrict__ A, const bf16* __restrict__ Bt,
    const float* __restrict__ bias, void* __restrict__ outp, void* __restrict__ outp2,
    int M, int N, int K, int lda) {
  __shared__ __align__(16) bf16 As[3][128 * 32];
  __shared__ __align__(16) bf16 Bs[3][128 * 32];
  int t = threadIdx.x;
  int wave = t >> 6, lane = t & 63;
  int lm = lane & 15, lg = lane >> 4;
  int m0 = blockIdx.y * 128, n0 = blockIdx.x * 128;
  size_t koff = (size_t)blockIdx.z * K;
  int wm = (wave >> 1) * 64, wn = (wave & 1) * 64;
  f32x4 acc[4][4] = {};

  int srow = t >> 2, sslot = t & 3;
  int scol = (sslot ^ ((srow >> 1) & 3)) * 8;
  const bf16* Ag = A + (size_t)(m0 + srow) * lda + koff + scol;
  const bf16* Bg = Bt + (size_t)(n0 + srow) * lda + koff + scol;
  size_t half = (size_t)64 * lda;
  int rsw = (lm >> 1) & 3;
  int nk = K >> 5;

  gll16(Ag, As[0] + t * 8);
  gll16(Ag + half, As[0] + 2048 + t * 8);
  gll16(Bg, Bs[0] + t * 8);
  gll16(Bg + half, Bs[0] + 2048 + t * 8);
  if (nk > 1) {
    gll16(Ag + 32, As[1] + t * 8);
    gll16(Ag + 32 + half, As[1] + 2048 + t * 8);
    gll16(Bg + 32, Bs[1] + t * 8);
    gll16(Bg + 32 + half, Bs[1] + 2048 + t * 8);
  }

  int buf = 0;
  for (int j = 0; j < nk; ++j) {
    if (j + 1 < nk) __builtin_amdgcn_s_waitcnt(WAITCNT_VM4);
    else            __builtin_amdgcn_s_waitcnt(WAITCNT_VM0);
    __builtin_amdgcn_s_barrier();
    if (j + 2 < nk) {
      int k2 = (j + 2) << 5;
      int nbuf = buf + 2; if (nbuf >= 3) nbuf -= 3;
      bf16* Ad = As[nbuf];
      bf16* Bd = Bs[nbuf];
      gll16(Ag + k2, Ad + t * 8);
      gll16(Ag + k2 + half, Ad + 2048 + t * 8);
      gll16(Bg + k2, Bd + t * 8);
      gll16(Bg + k2 + half, Bd + 2048 + t * 8);
    }
    const bf16* Ab = As[buf];
    const bf16* Bb = Bs[buf];
    if (++buf == 3) buf = 0;
    bf16x8 af[4], bfr[4];
    #pragma unroll
    for (int i = 0; i < 4; i++)
      af[i] = *(const bf16x8*)(Ab + (wm + i * 16 + lm) * 32 + (lg ^ rsw) * 8);
    #pragma unroll
    for (int j2 = 0; j2 < 4; j2++)
      bfr[j2] = *(const bf16x8*)(Bb + (wn + j2 * 16 + lm) * 32 + (lg ^ rsw) * 8);
    #pragma unroll
    for (int i = 0; i < 4; i++)
      #pragma unroll
      for (int j2 = 0; j2 < 4; j2++)
        acc[i][j2] = __builtin_amdgcn_mfma_f32_16x16x32_bf16(af[i], bfr[j2], acc[i][j2], 0, 0, 0);
  }

  bf16* pout = (MODE == 5) ? ((blockIdx.z == 0) ? (bf16*)outp : (bf16*)outp2) : (bf16*)outp;

  #pragma unroll
  for (int i = 0; i < 4; i++) {
    int row = m0 + wm + i * 16 + lg * 4;
    #pragma unroll
    for (int j = 0; j < 4; j++) {
      int col = n0 + wn + j * 16 + lm;
      float bcol = (MODE == 5) ? 0.f : bias[col];
      #pragma unroll
      for (int r = 0; r < 4; r++) {
        float v = acc[i][j][r] + bcol;
        int rr = row + r;
        if (MODE == 0) {
          int which = col >> 10, d = col & 1023;
          int hh = d >> 6, dh = d & 63;
          int bb = rr >> 11, s = rr & 2047;
          ((bf16*)outp)[(size_t)which * ((size_t)B_*H_*S_*DH_) +
              ((size_t)(bb * H_ + hh) * S_ + s) * DH_ + dh] = (bf16)v;
        } else if (MODE == 2) {
          ((bf16*)outp)[(size_t)rr * N + col] = (bf16)gelu_fast(v);
        } else {
          pout[(size_t)rr * N + col] = (bf16)v;
        }
      }
    }
  }
}

// ---------------- Flash attention v6 ----------------
// Round-4 single-buffer staging (25 KB LDS -> 5-6 blocks/CU; TLP beats ILP here)
// + banding + balanced 2-way KV-chunk split + heavy-first dispatch.
// Fixed-max softmax => chunks combine additively.
#define PSTR 68
__global__ __launch_bounds__(256, 5) void attn_kernel(
    const bf16* __restrict__ q, const bf16* __restrict__ k,
    const bf16* __restrict__ vT, bf16* __restrict__ pbuf, float* __restrict__ rsbuf) {
  __shared__ __align__(16) bf16 Ks[64 * 64];
  __shared__ __align__(16) bf16 Vs[64 * 64];
  __shared__ __align__(16) bf16 Ps[4 * 16 * PSTR];
  int t = threadIdx.x, wave = t >> 6, lane = t & 63;
  int lm = lane & 15, lg = lane >> 4;
  int qt = blockIdx.x, q0 = qt * 64;
  int h = 15 - blockIdx.y;               // heavy (small-slope) heads dispatch first
  int b = blockIdx.z >> 1, c = blockIdx.z & 1;
  size_t base = (size_t)(b * H_ + h) * ((size_t)S_ * DH_);
  const bf16* Q = q + base;
  const bf16* K = k + base;
  const bf16* V = vT + base;   // [DH][S]
  const float LOG2E = 1.4426950408889634f;
  float sl2 = exp2f(-0.5f * (float)(h + 1)) * LOG2E;
  float nslope = -sl2;
  const float qscale = 0.125f * LOG2E;
  const float FMAX = 8.0f;

  int W = (int)(24.0f / sl2);
  int jlo = (q0 - W) >> 6; if (jlo < 0) jlo = 0;
  int jhi = ((q0 + 63 + W) >> 6) + 1; if (jhi > S_ / 64) jhi = S_ / 64;
  int n = jhi - jlo, nc0 = (n + 1) >> 1;
  int cjlo = c ? jlo + nc0 : jlo;
  int cjhi = c ? jhi : jlo + nc0;
  int slot = ((b * H_ + h) * 32 + qt) * 2 + c;
  bf16* Pout = pbuf + (size_t)slot * 4096;
  float* Rout = rsbuf + (size_t)slot * 64;

  if (cjlo >= cjhi) {   // empty chunk: zero-fill partial (ws is poisoned)
    uint4 z = {0, 0, 0, 0};
    *(uint4*)(Pout + t * 8) = z;
    *(uint4*)(Pout + 2048 + t * 8) = z;
    if (t < 64) Rout[t] = 0.f;
    return;
  }

  bf16x8 qf[2];
  #pragma unroll
  for (int h2 = 0; h2 < 2; h2++) {
    bf16x8 v = *(const bf16x8*)(Q + (size_t)(q0 + wave * 16 + lm) * DH_ + h2 * 32 + lg * 8);
    #pragma unroll
    for (int e = 0; e < 8; e++) v[e] = (bf16)((float)v[e] * qscale);
    qf[h2] = v;
  }

  int row0 = t >> 3, jslot = t & 7;
  int gsw = (jslot ^ (row0 & 7)) << 3;
  const bf16* Ksrc0 = K + (size_t)row0 * DH_ + gsw;
  const bf16* Vsrc0 = V + (size_t)row0 * S_ + gsw;

  f32x4 oacc[4] = {};
  float rs[4] = {0.f, 0.f, 0.f, 0.f};
  int psw = lm & 7;

  for (int jj = cjlo; jj < cjhi; ++jj) {
    int jt = jj << 6;
    __syncthreads();   // prior tile's readers done
    gll16(Ksrc0 + (size_t)jt * DH_, Ks + (size_t)t * 8);
    gll16(Ksrc0 + (size_t)(jt + 32) * DH_, Ks + (size_t)(t + 256) * 8);
    gll16(Vsrc0 + jt, Vs + (size_t)t * 8);
    gll16(Vsrc0 + (size_t)32 * S_ + jt, Vs + (size_t)(t + 256) * 8);
    __syncthreads();   // drains vmcnt

    f32x4 sc[4];
    #pragma unroll
    for (int tt = 0; tt < 4; tt++) {
      f32x4 a = {-FMAX, -FMAX, -FMAX, -FMAX};
      int krow = tt * 16 + lm;
      bf16x8 kb0 = *(const bf16x8*)(Ks + (size_t)(krow * 8 + (lg ^ psw)) * 8);
      bf16x8 kb1 = *(const bf16x8*)(Ks + (size_t)(krow * 8 + ((lg + 4) ^ psw)) * 8);
      a = __builtin_amdgcn_mfma_f32_16x16x32_bf16(qf[0], kb0, a, 0, 0, 0);
      a = __builtin_amdgcn_mfma_f32_16x16x32_bf16(qf[1], kb1, a, 0, 0, 0);
      sc[tt] = a;
    }

    bf16* Pw = Ps + wave * (16 * PSTR);
    int i0 = q0 + wave * 16 + lg * 4;
    #pragma unroll
    for (int tt = 0; tt < 4; tt++) {
      float f0 = (float)(i0 - jt - tt * 16 - lm);
      #pragma unroll
      for (int r = 0; r < 4; r++) {
        float s2 = fmaf(nslope, fabsf(f0 + (float)r), sc[tt][r]);
        float p = __builtin_amdgcn_exp2f(s2);
        rs[r] += p;
        Pw[(lg * 4 + r) * PSTR + tt * 16 + lm] = (bf16)p;
      }
    }

    bf16x8 ap0 = *(const bf16x8*)(Pw + lm * PSTR + lg * 8);
    bf16x8 ap1 = *(const bf16x8*)(Pw + lm * PSTR + 32 + lg * 8);
    #pragma unroll
    for (int tt = 0; tt < 4; tt++) {
      int vrow = tt * 16 + lm;
      bf16x8 vb0 = *(const bf16x8*)(Vs + (size_t)(vrow * 8 + (lg ^ psw)) * 8);
      bf16x8 vb1 = *(const bf16x8*)(Vs + (size_t)(vrow * 8 + ((lg + 4) ^ psw)) * 8);
      oacc[tt] = __builtin_amdgcn_mfma_f32_16x16x32_bf16(ap0, vb0, oacc[tt], 0, 0, 0);
      oacc[tt] = __builtin_amdgcn_mfma_f32_16x16x32_bf16(ap1, vb1, oacc[tt], 0, 0, 0);
    }
  }

  #pragma unroll
  for (int r = 0; r < 4; r++) {
    #pragma unroll
    for (int off = 1; off < 16; off <<= 1)
      rs[r] += __shfl_xor(rs[r], off, 16);
  }

  #pragma unroll
  for (int r = 0; r < 4; r++) {
    int lrow = wave * 16 + lg * 4 + r;
    if (lm == 0) Rout[lrow] = rs[r];
    #pragma unroll
    for (int tt = 0; tt < 4; tt++)
      Pout[lrow * 64 + tt * 16 + lm] = (bf16)oacc[tt][r];
  }
}

// ---------------- attn combine: ao = (p0+p1)/(rs0+rs1) ----------------
__global__ __launch_bounds__(256) void attn_combine_kernel(
    const bf16* __restrict__ pbuf, const float* __restrict__ rsbuf,
    bf16* __restrict__ ao) {
  int qt = blockIdx.x, h = blockIdx.y, b = blockIdx.z;
  int slot0 = ((b * H_ + h) * 32 + qt) * 2;
  int t = threadIdx.x;
  int row = t >> 2, cg = (t & 3) * 16;
  const bf16* P0 = pbuf + (size_t)slot0 * 4096 + row * 64 + cg;
  const bf16* P1 = pbuf + (size_t)(slot0 + 1) * 4096 + row * 64 + cg;
  float inv = 1.0f / (rsbuf[(size_t)slot0 * 64 + row] + rsbuf[(size_t)(slot0 + 1) * 64 + row]);
  bf16x8 a0 = *(const bf16x8*)P0, a1 = *(const bf16x8*)(P0 + 8);
  bf16x8 b0 = *(const bf16x8*)P1, b1 = *(const bf16x8*)(P1 + 8);
  bf16x8 o0, o1;
  #pragma unroll
  for (int e = 0; e < 8; e++) {
    o0[e] = (bf16)(((float)a0[e] + (float)b0[e]) * inv);
    o1[e] = (bf16)(((float)a1[e] + (float)b1[e]) * inv);
  }
  bf16* dst = ao + ((size_t)(b * S_) + qt * 64 + row) * D_ + h * 64 + cg;
  *(bf16x8*)dst = o0;
  *(bf16x8*)(dst + 8) = o1;
}

extern "C" void kernel_launch(void* const* d_in, const int* in_sizes, int n_in,
                              void* d_out, int out_size, void* d_ws, size_t ws_size,
                              hipStream_t stream) {
  const float* x      = (const float*)d_in[0];
  const float* scale1 = (const float*)d_in[1];
  const float* scale2 = (const float*)d_in[2];
  const float* w_qkv  = (const float*)d_in[3];
  const float* b_qkv  = (const float*)d_in[4];
  const float* w_out  = (const float*)d_in[5];
  const float* b_out  = (const float*)d_in[6];
  const float* w1     = (const float*)d_in[7];
  const float* b1     = (const float*)d_in[8];
  const float* w2     = (const float*)d_in[9];
  const float* b2     = (const float*)d_in[10];

  char* ws = (char*)d_ws;
  const size_t MB = 1024 * 1024;
  // layout (80 MB):
  bf16* xn    = (bf16*)(ws + 0);        // 0-8:   xn -> ao -> ffn2 partial 0
  bf16* qb    = (bf16*)(ws + 8*MB);     // 8-16:  q -> xn2
  bf16* kb    = (bf16*)(ws + 16*MB);    // 16-24: k -> out-proj partial 0 -> hbuf[0:8]
  bf16* vb    = (bf16*)(ws + 24*MB);    // 24-32: v -> out-proj partial 1 -> hbuf[8:16]
  bf16* vT    = (bf16*)(ws + 32*MB);    // 32-40: vT -> hbuf[16:24]
  bf16* wqkvT = (bf16*)(ws + 40*MB);    // 40-46: wqkvT; dead after qkv -> attn rsbuf
  bf16* woutT = (bf16*)(ws + 46*MB);    // 46-48: woutT -> hbuf[30:32]
  bf16* w1T   = (bf16*)(ws + 48*MB);    // 48-56: w1T -> ffn2 partial 1
  bf16* w2T   = (bf16*)(ws + 56*MB);    // 56-64: w2T
  float* x2   = (float*)(ws + 64*MB);   // 64-80: attn o-partials (16MB), then x2 fp32
  bf16* xn2   = qb;
  bf16* pp0   = kb;                     // out-proj partials
  bf16* pp1   = vb;
  bf16* hbuf  = kb;                     // 16-48 [M,DFF]
  bf16* qp0   = xn;                     // ffn2 partials
  bf16* qp1   = w1T;
  bf16* ao    = xn;
  bf16* pbuf  = (bf16*)(ws + 64*MB);    // attn o-partials (dead once combine runs)
  float* rsbuf = (float*)(ws + 40*MB);  // attn row-sums (0.5MB; wqkvT dead by then)

  dim3 blk(256);
  wtrans_kernel<<<dim3(3072/32, 1024/32), blk, 0, stream>>>(w_qkv, wqkvT, 1024, 3072);
  wtrans_kernel<<<dim3(1024/32, 1024/32), blk, 0, stream>>>(w_out, woutT, 1024, 1024);
  wtrans_kernel<<<dim3(4096/32, 1024/32), blk, 0, stream>>>(w1, w1T, 1024, 4096);
  wtrans_kernel<<<dim3(1024/32, 4096/32), blk, 0, stream>>>(w2, w2T, 4096, 1024);

  rmsnorm_kernel<<<dim3(M_), blk, 0, stream>>>(x, scale1, xn);

  gemm_kernel<0><<<dim3(3072/128, M_/128, 1), blk, 0, stream>>>(
      xn, wqkvT, b_qkv, qb, nullptr, M_, 3072, 1024, 1024);

  vtrans_kernel<<<dim3(S_/32, DH_/32, B_*H_), blk, 0, stream>>>(vb, vT);

  attn_kernel<<<dim3(S_/64, H_, B_*2), blk, 0, stream>>>(qb, kb, vT, pbuf, rsbuf);
  attn_combine_kernel<<<dim3(S_/64, H_, B_), blk, 0, stream>>>(pbuf, rsbuf, ao);

  // out-proj split-K=2: bf16 partials, then fused reduce+residual+bias+rmsnorm
  gemm_kernel<5><<<dim3(1024/128, M_/128, 2), blk, 0, stream>>>(
      ao, woutT, nullptr, pp0, pp1, M_, 1024, 512, 1024);
  reduce_rms_kernel<<<dim3(M_), blk, 0, stream>>>(pp0, pp1, x, b_out, scale2, x2, xn2);

  gemm_kernel<2><<<dim3(4096/128, M_/128, 1), blk, 0, stream>>>(
      xn2, w1T, b1, hbuf, nullptr, M_, 4096, 1024, 1024);

  // ffn2 split-K=2: bf16 partials, then fused reduce+residual+bias -> d_out
  gemm_kernel<5><<<dim3(1024/128, M_/128, 2), blk, 0, stream>>>(
      hbuf, w2T, nullptr, qp0, qp1, M_, 1024, 2048, 4096);
  reduce_out_kernel<<<dim3(M_), blk, 0, stream>>>(qp0, qp1, x2, b2, (float*)d_out);
}